// Round 1
// baseline (579.095 us; speedup 1.0000x reference)
//
#include <hip/hip_runtime.h>
#include <math.h>

// ---------------------------------------------------------------------------
// GoBERT: GATConv(4x32) -> BN -> GCNConv(128) -> BN -> GlobalAttention -> FC
// N=50000 nodes, E=800000 edges, Fin=128, H=4, C1=32, C2=128, 64 graphs.
// Strategy: build CSR by dst (count/scan/scatter), then one wave per dst node
// does exact online softmax + message accumulation in registers (no float
// atomics). fp32 everywhere (threshold 5.3e-3; bf16 MFMA deferred).
// ---------------------------------------------------------------------------

#define NEG_SLOPE 0.2f

__device__ __forceinline__ int lower_bound_i(const int* a, int n, int key) {
    int lo = 0, hi = n;
    while (lo < hi) {
        int mid = (lo + hi) >> 1;
        if (a[mid] < key) lo = mid + 1; else hi = mid;
    }
    return lo;
}

// ---------------- GEMM: C[N,128] = f(A)[N,128] @ W[128,128] ----------------
// mode 0: f = identity (layer-1: h = x @ W_gat)
// mode 1: f(a,k) = bn1w[k]*elu(a + b_gat[k]) + bn1b[k]   (layer-2 input)
__global__ __launch_bounds__(256) void k_gemm(
    const float* __restrict__ A, const float* __restrict__ W,
    float* __restrict__ C, int N, int mode,
    const float* __restrict__ pb, const float* __restrict__ pw,
    const float* __restrict__ pb2)
{
    __shared__ float sW[64 * 128];    // half of W (K-split)
    __shared__ float sA[32 * 132];    // 32 rows, padded stride 132

    const int tid = threadIdx.x;
    const int n0 = blockIdx.x * 32;

    // Load A tile (with optional fused pointwise transform)
    for (int i = tid * 4; i < 32 * 128; i += 1024) {
        int r = i >> 7;
        int k = i & 127;
        int gn = n0 + r;
        float4 v = make_float4(0.f, 0.f, 0.f, 0.f);
        if (gn < N) v = *(const float4*)(A + (size_t)gn * 128 + k);
        if (mode) {
            float t;
            t = v.x + pb[k + 0]; t = (t > 0.f) ? t : expm1f(t); v.x = t * pw[k + 0] + pb2[k + 0];
            t = v.y + pb[k + 1]; t = (t > 0.f) ? t : expm1f(t); v.y = t * pw[k + 1] + pb2[k + 1];
            t = v.z + pb[k + 2]; t = (t > 0.f) ? t : expm1f(t); v.z = t * pw[k + 2] + pb2[k + 2];
            t = v.w + pb[k + 3]; t = (t > 0.f) ? t : expm1f(t); v.w = t * pw[k + 3] + pb2[k + 3];
        }
        *(float4*)(sA + r * 132 + k) = v;
    }

    const int c8 = tid & 15;          // 16 col-groups of 8
    const int cb = c8 * 8;
    const int r0 = tid >> 4;          // 0..15
    const int r1 = r0 + 16;

    float acc0[8], acc1[8];
#pragma unroll
    for (int j = 0; j < 8; j++) { acc0[j] = 0.f; acc1[j] = 0.f; }

    for (int kt = 0; kt < 128; kt += 64) {
        for (int i = tid * 4; i < 64 * 128; i += 1024)
            *(float4*)(sW + i) = *(const float4*)(W + (size_t)kt * 128 + i);
        __syncthreads();
#pragma unroll 4
        for (int k = 0; k < 64; k++) {
            float a0 = sA[r0 * 132 + kt + k];
            float a1 = sA[r1 * 132 + kt + k];
            float w8[8];
            *(float4*)(w8)     = *(const float4*)(sW + k * 128 + cb);
            *(float4*)(w8 + 4) = *(const float4*)(sW + k * 128 + cb + 4);
#pragma unroll
            for (int j = 0; j < 8; j++) {
                acc0[j] += a0 * w8[j];
                acc1[j] += a1 * w8[j];
            }
        }
        __syncthreads();
    }

    int gn0 = n0 + r0, gn1 = n0 + r1;
    if (gn0 < N) {
        *(float4*)(C + (size_t)gn0 * 128 + cb)     = make_float4(acc0[0], acc0[1], acc0[2], acc0[3]);
        *(float4*)(C + (size_t)gn0 * 128 + cb + 4) = make_float4(acc0[4], acc0[5], acc0[6], acc0[7]);
    }
    if (gn1 < N) {
        *(float4*)(C + (size_t)gn1 * 128 + cb)     = make_float4(acc1[0], acc1[1], acc1[2], acc1[3]);
        *(float4*)(C + (size_t)gn1 * 128 + cb + 4) = make_float4(acc1[4], acc1[5], acc1[6], acc1[7]);
    }
}

// ---------------- attention coefficients: a_src/a_dst [N,4] ----------------
__global__ __launch_bounds__(64) void k_attn(
    const float* __restrict__ h, const float* __restrict__ att_s,
    const float* __restrict__ att_d, float* __restrict__ aS,
    float* __restrict__ aD, int N)
{
    int n = blockIdx.x;
    int l = threadIdx.x;
    float v0 = h[(size_t)n * 128 + l];
    float v1 = h[(size_t)n * 128 + 64 + l];
    float s0 = v0 * att_s[l],      d0 = v0 * att_d[l];
    float s1 = v1 * att_s[64 + l], d1 = v1 * att_d[64 + l];
#pragma unroll
    for (int m = 1; m < 32; m <<= 1) {   // reduce within 32-lane halves
        s0 += __shfl_xor(s0, m); d0 += __shfl_xor(d0, m);
        s1 += __shfl_xor(s1, m); d1 += __shfl_xor(d1, m);
    }
    if (l == 0)  { aS[(size_t)n*4+0]=s0; aS[(size_t)n*4+2]=s1; aD[(size_t)n*4+0]=d0; aD[(size_t)n*4+2]=d1; }
    if (l == 32) { aS[(size_t)n*4+1]=s0; aS[(size_t)n*4+3]=s1; aD[(size_t)n*4+1]=d0; aD[(size_t)n*4+3]=d1; }
}

// ---------------- CSR build ----------------
__global__ __launch_bounds__(256) void k_count(const int* __restrict__ ei,
                                               int* __restrict__ deg, int E)
{
    int e = blockIdx.x * 256 + threadIdx.x;
    if (e < E) atomicAdd(&deg[ei[E + e]], 1);
}

__global__ __launch_bounds__(1024) void k_scan(const int* __restrict__ deg,
                                               int* __restrict__ offs,
                                               int* __restrict__ cur, int N)
{
    __shared__ int wsum[16];
    const int tid = threadIdx.x, lane = tid & 63, wid = tid >> 6;
    int carry = 0;
    for (int base = 0; base < N; base += 1024) {
        int i = base + tid;
        int v = (i < N) ? deg[i] : 0;
        int incl = v;
#pragma unroll
        for (int off = 1; off < 64; off <<= 1) {
            int t = __shfl_up(incl, off, 64);
            if (lane >= off) incl += t;
        }
        if (lane == 63) wsum[wid] = incl;
        __syncthreads();
        int prefix = 0, total = 0;
        for (int w = 0; w < 16; w++) {
            int x = wsum[w];
            total += x;
            if (w < wid) prefix += x;
        }
        int excl = carry + prefix + incl - v;
        if (i < N) { offs[i] = excl; cur[i] = excl; }
        carry += total;
        __syncthreads();
    }
    if (tid == 0) offs[N] = carry;
}

__global__ __launch_bounds__(256) void k_scatter(const int* __restrict__ ei,
                                                 int* __restrict__ cur,
                                                 int* __restrict__ csr, int E)
{
    int e = blockIdx.x * 256 + threadIdx.x;
    if (e < E) {
        int d = ei[E + e];
        int slot = atomicAdd(&cur[d], 1);
        csr[slot] = ei[e];
    }
}

// ---------------- GAT aggregation: one wave per dst node ----------------
// slot 0 = self loop, slots 1..deg = CSR entries. Online softmax per head.
__global__ __launch_bounds__(64) void k_gat_aggr(
    const float* __restrict__ h, const float* __restrict__ aS,
    const float* __restrict__ aD, const int* __restrict__ offs,
    const int* __restrict__ csr, float* __restrict__ raw1, int N)
{
    const int n = blockIdx.x;
    const int lane = threadIdx.x;
    const int beg = offs[n];
    const int cnt = offs[n + 1] - beg + 1;   // + self loop
    const float4 ad = *(const float4*)(aD + (size_t)n * 4);
    const int hA = lane >> 5;                // head sel: 0/1 (chs l), 2/3 via +2

    __shared__ int   s_src[64];
    __shared__ float s_p[64 * 4];

    float m0 = -INFINITY, m1 = -INFINITY, m2 = -INFINITY, m3 = -INFINITY;
    float t0 = 0.f, t1 = 0.f, t2 = 0.f, t3 = 0.f;
    float acc0 = 0.f, acc1 = 0.f;

    for (int base = 0; base < cnt; base += 64) {
        int idx = base + lane;
        bool valid = idx < cnt;
        int src = n;
        if (valid && idx > 0) src = csr[beg + idx - 1];
        float l0 = -INFINITY, l1 = -INFINITY, l2 = -INFINITY, l3 = -INFINITY;
        if (valid) {
            float4 as = *(const float4*)(aS + (size_t)src * 4);
            l0 = as.x + ad.x; l0 = (l0 > 0.f) ? l0 : NEG_SLOPE * l0;
            l1 = as.y + ad.y; l1 = (l1 > 0.f) ? l1 : NEG_SLOPE * l1;
            l2 = as.z + ad.z; l2 = (l2 > 0.f) ? l2 : NEG_SLOPE * l2;
            l3 = as.w + ad.w; l3 = (l3 > 0.f) ? l3 : NEG_SLOPE * l3;
        }
        // chunk max per head (butterfly over 64 lanes)
        float c0 = l0, c1 = l1, c2 = l2, c3 = l3;
#pragma unroll
        for (int msk = 1; msk < 64; msk <<= 1) {
            c0 = fmaxf(c0, __shfl_xor(c0, msk));
            c1 = fmaxf(c1, __shfl_xor(c1, msk));
            c2 = fmaxf(c2, __shfl_xor(c2, msk));
            c3 = fmaxf(c3, __shfl_xor(c3, msk));
        }
        float nm0 = fmaxf(m0, c0), nm1 = fmaxf(m1, c1);
        float nm2 = fmaxf(m2, c2), nm3 = fmaxf(m3, c3);
        float e0 = expf(m0 - nm0), e1 = expf(m1 - nm1);
        float e2 = expf(m2 - nm2), e3 = expf(m3 - nm3);
        t0 *= e0; t1 *= e1; t2 *= e2; t3 *= e3;
        float scA = hA ? e1 : e0;
        float scB = hA ? e3 : e2;
        acc0 *= scA; acc1 *= scB;
        m0 = nm0; m1 = nm1; m2 = nm2; m3 = nm3;

        float p0 = valid ? expf(l0 - nm0) : 0.f;
        float p1 = valid ? expf(l1 - nm1) : 0.f;
        float p2 = valid ? expf(l2 - nm2) : 0.f;
        float p3 = valid ? expf(l3 - nm3) : 0.f;
        float q0 = p0, q1 = p1, q2 = p2, q3 = p3;
#pragma unroll
        for (int msk = 1; msk < 64; msk <<= 1) {
            q0 += __shfl_xor(q0, msk);
            q1 += __shfl_xor(q1, msk);
            q2 += __shfl_xor(q2, msk);
            q3 += __shfl_xor(q3, msk);
        }
        t0 += q0; t1 += q1; t2 += q2; t3 += q3;

        s_src[lane] = src;
        s_p[lane * 4 + 0] = p0; s_p[lane * 4 + 1] = p1;
        s_p[lane * 4 + 2] = p2; s_p[lane * 4 + 3] = p3;
        __syncthreads();
        int cc = min(64, cnt - base);
        for (int j = 0; j < cc; j++) {
            const float* hr = h + (size_t)s_src[j] * 128;
            float pA = s_p[j * 4 + hA];
            float pB = s_p[j * 4 + 2 + hA];
            acc0 += pA * hr[lane];
            acc1 += pB * hr[lane + 64];
        }
        __syncthreads();
    }
    float sA_ = (hA ? t1 : t0) + 1e-16f;
    float sB_ = (hA ? t3 : t2) + 1e-16f;
    raw1[(size_t)n * 128 + lane]      = acc0 / sA_;
    raw1[(size_t)n * 128 + 64 + lane] = acc1 / sB_;
}

// ---------------- GCN aggregation + fused BN2/ELU/gate ----------------
__global__ __launch_bounds__(64) void k_gcn_aggr(
    const float* __restrict__ h2, const int* __restrict__ offs,
    const int* __restrict__ csr, const float* __restrict__ bgcn,
    const float* __restrict__ bn2w, const float* __restrict__ bn2b,
    const float* __restrict__ wgate, const float* __restrict__ bgate,
    float* __restrict__ out2, float* __restrict__ gate, int N)
{
    const int n = blockIdx.x;
    const int lane = threadIdx.x;
    const int beg = offs[n];
    const int cnt = offs[n + 1] - beg + 1;   // in-degree + self loop
    const float dn = rsqrtf((float)cnt);

    __shared__ int   s_src[64];
    __shared__ float s_w[64];

    float acc0 = 0.f, acc1 = 0.f;
    for (int base = 0; base < cnt; base += 64) {
        int idx = base + lane;
        bool valid = idx < cnt;
        int src = n;
        float w = dn * dn;                   // self-loop norm
        if (valid && idx > 0) {
            src = csr[beg + idx - 1];
            int ds = offs[src + 1] - offs[src] + 1;
            w = rsqrtf((float)ds) * dn;
        }
        s_src[lane] = src;
        s_w[lane] = valid ? w : 0.f;
        __syncthreads();
        int cc = min(64, cnt - base);
        for (int j = 0; j < cc; j++) {
            const float* r = h2 + (size_t)s_src[j] * 128;
            float wj = s_w[j];
            acc0 += wj * r[lane];
            acc1 += wj * r[lane + 64];
        }
        __syncthreads();
    }
    float v0 = acc0 + bgcn[lane];
    v0 = (v0 > 0.f) ? v0 : expm1f(v0);
    v0 = v0 * bn2w[lane] + bn2b[lane];
    float v1 = acc1 + bgcn[lane + 64];
    v1 = (v1 > 0.f) ? v1 : expm1f(v1);
    v1 = v1 * bn2w[lane + 64] + bn2b[lane + 64];
    out2[(size_t)n * 128 + lane]      = v0;
    out2[(size_t)n * 128 + 64 + lane] = v1;

    float g = v0 * wgate[lane] + v1 * wgate[lane + 64];
#pragma unroll
    for (int msk = 1; msk < 64; msk <<= 1) g += __shfl_xor(g, msk);
    if (lane == 0) gate[n] = g + bgate[0];
}

// ---------------- Global attention pooling + FC: one block per graph -------
__global__ __launch_bounds__(256) void k_pool(
    const float* __restrict__ out2, const float* __restrict__ gate,
    const int* __restrict__ batch, const float* __restrict__ wfc,
    const float* __restrict__ bfc, float* __restrict__ out, int N)
{
    __shared__ float red[256];
    __shared__ int range[2];
    const int g = blockIdx.x;
    const int tid = threadIdx.x;

    if (tid == 0) {
        range[0] = lower_bound_i(batch, N, g);
        range[1] = lower_bound_i(batch, N, g + 1);
    }
    __syncthreads();
    const int lo = range[0], hi = range[1];
    if (lo >= hi) {                         // empty graph: rep = 0
        if (tid == 0) out[g] = bfc[0];
        return;
    }
    // pass 1: max gate
    float lm = -INFINITY;
    for (int i = lo + tid; i < hi; i += 256) lm = fmaxf(lm, gate[i]);
    red[tid] = lm; __syncthreads();
    for (int s = 128; s > 0; s >>= 1) {
        if (tid < s) red[tid] = fmaxf(red[tid], red[tid + s]);
        __syncthreads();
    }
    float gm = red[0]; __syncthreads();
    // pass 2: sum exp
    float ls = 0.f;
    for (int i = lo + tid; i < hi; i += 256) ls += expf(gate[i] - gm);
    red[tid] = ls; __syncthreads();
    for (int s = 128; s > 0; s >>= 1) {
        if (tid < s) red[tid] += red[tid + s];
        __syncthreads();
    }
    float inv = 1.f / (red[0] + 1e-16f); __syncthreads();
    // pass 3: weighted channel sums
    const int c = tid & 127, half = tid >> 7;
    float acc = 0.f;
    for (int i = lo + half; i < hi; i += 2) {
        float w = expf(gate[i] - gm) * inv;
        acc += w * out2[(size_t)i * 128 + c];
    }
    red[tid] = acc; __syncthreads();
    float dotp = 0.f;
    if (tid < 128) {
        float rep = red[tid] + red[tid + 128];
        dotp = rep * wfc[tid];
    }
    __syncthreads();
    red[tid] = dotp; __syncthreads();
    for (int s = 128; s > 0; s >>= 1) {
        if (tid < s) red[tid] += red[tid + s];
        __syncthreads();
    }
    if (tid == 0) out[g] = red[0] + bfc[0];
}

// ---------------------------------------------------------------------------
extern "C" void kernel_launch(void* const* d_in, const int* in_sizes, int n_in,
                              void* d_out, int out_size, void* d_ws, size_t ws_size,
                              hipStream_t stream) {
    const float* x     = (const float*)d_in[0];
    const int*   ei    = (const int*)d_in[1];
    const int*   batch = (const int*)d_in[2];
    const float* Wgat  = (const float*)d_in[3];
    const float* atts  = (const float*)d_in[4];
    const float* attd  = (const float*)d_in[5];
    const float* bgat  = (const float*)d_in[6];
    const float* bn1w  = (const float*)d_in[7];
    const float* bn1b  = (const float*)d_in[8];
    const float* Wgcn  = (const float*)d_in[9];
    const float* bgcn  = (const float*)d_in[10];
    const float* bn2w  = (const float*)d_in[11];
    const float* bn2b  = (const float*)d_in[12];
    const float* wgate = (const float*)d_in[13];
    const float* bgate = (const float*)d_in[14];
    const float* wfc   = (const float*)d_in[15];
    const float* bfc   = (const float*)d_in[16];
    float* out = (float*)d_out;

    const int N = in_sizes[0] / 128;
    const int E = in_sizes[1] / 2;

    // workspace layout
    float* bufA = (float*)d_ws;                    // h, then h2       [N*128]
    float* bufB = bufA + (size_t)N * 128;          // raw1, then out2  [N*128]
    float* aS   = bufB + (size_t)N * 128;          // [N*4]
    float* aD   = aS + (size_t)N * 4;              // [N*4]
    float* gate = aD + (size_t)N * 4;              // [N]
    int* offs = (int*)(gate + N);                  // [N+1]
    int* cur  = offs + (N + 1);                    // [N]
    int* csr  = cur + N;                           // [E]
    int* deg  = csr + E;                           // [N]

    hipMemsetAsync(deg, 0, (size_t)N * sizeof(int), stream);

    const int gemm_blocks = (N + 31) / 32;
    k_gemm<<<gemm_blocks, 256, 0, stream>>>(x, Wgat, bufA, N, 0, nullptr, nullptr, nullptr);
    k_attn<<<N, 64, 0, stream>>>(bufA, atts, attd, aS, aD, N);
    k_count<<<(E + 255) / 256, 256, 0, stream>>>(ei, deg, E);
    k_scan<<<1, 1024, 0, stream>>>(deg, offs, cur, N);
    k_scatter<<<(E + 255) / 256, 256, 0, stream>>>(ei, cur, csr, E);
    k_gat_aggr<<<N, 64, 0, stream>>>(bufA, aS, aD, offs, csr, bufB, N);
    k_gemm<<<gemm_blocks, 256, 0, stream>>>(bufB, Wgcn, bufA, N, 1, bgat, bn1w, bn1b);
    k_gcn_aggr<<<N, 64, 0, stream>>>(bufA, offs, csr, bgcn, bn2w, bn2b, wgate, bgate, bufB, gate, N);
    k_pool<<<64, 256, 0, stream>>>(bufB, gate, batch, wfc, bfc, out, N);
}

// Round 2
// 453.198 us; speedup vs baseline: 1.2778x; 1.2778x over previous
//
#include <hip/hip_runtime.h>
#include <math.h>

// GoBERT: GATConv(4x32) -> BN -> GCNConv(128) -> BN -> GlobalAttention -> FC
// Round 1: fuse attn coeffs into GEMM1 epilogue; fuse gate+fc dots into GCN
// aggregation (out2 never materialized); unnormalized softmax (no max pass);
// 4 nodes per 256-thread block in aggregators, barrier-free (per-wave LDS).

#define NEG_SLOPE 0.2f

__device__ __forceinline__ int lower_bound_i(const int* a, int n, int key) {
    int lo = 0, hi = n;
    while (lo < hi) {
        int mid = (lo + hi) >> 1;
        if (a[mid] < key) lo = mid + 1; else hi = mid;
    }
    return lo;
}

// ---------------- GEMM: C[N,128] = f(A)[N,128] @ W[128,128] ----------------
// mode 0: f = id; epilogue also computes aS/aD = per-head att dots (GAT layer)
// mode 1: f(a,k) = bn1w[k]*elu(a + b_gat[k]) + bn1b[k]   (GCN layer input)
// 64 rows/block; thread = 4 rows x 8 cols; W streamed from global (L2).
__global__ __launch_bounds__(256) void k_gemm(
    const float* __restrict__ A, const float* __restrict__ W,
    float* __restrict__ C, int N, int mode,
    const float* __restrict__ pb, const float* __restrict__ pw,
    const float* __restrict__ pb2,
    const float* __restrict__ atts, const float* __restrict__ attd,
    float* __restrict__ aS, float* __restrict__ aD)
{
    __shared__ float sA[64 * 132];
    const int tid = threadIdx.x;
    const int n0 = blockIdx.x * 64;

    // stage A tile (fused pointwise transform for mode 1)
    for (int i = tid * 4; i < 64 * 128; i += 1024) {
        int r = i >> 7;
        int k = i & 127;
        int gn = n0 + r;
        float4 v = make_float4(0.f, 0.f, 0.f, 0.f);
        if (gn < N) v = *(const float4*)(A + (size_t)gn * 128 + k);
        if (mode) {
            float4 bv = *(const float4*)(pb + k);
            float4 wv = *(const float4*)(pw + k);
            float4 b2 = *(const float4*)(pb2 + k);
            float t;
            t = v.x + bv.x; t = (t > 0.f) ? t : expm1f(t); v.x = t * wv.x + b2.x;
            t = v.y + bv.y; t = (t > 0.f) ? t : expm1f(t); v.y = t * wv.y + b2.y;
            t = v.z + bv.z; t = (t > 0.f) ? t : expm1f(t); v.z = t * wv.z + b2.z;
            t = v.w + bv.w; t = (t > 0.f) ? t : expm1f(t); v.w = t * wv.w + b2.w;
        }
        *(float4*)(sA + r * 132 + k) = v;
    }
    __syncthreads();

    const int c8 = tid & 15;
    const int cb = c8 * 8;
    const int rg = tid >> 4;          // 0..15
    const int rbase = rg * 4;

    float acc[4][8];
#pragma unroll
    for (int r = 0; r < 4; r++)
#pragma unroll
        for (int c = 0; c < 8; c++) acc[r][c] = 0.f;

    for (int kb = 0; kb < 128; kb += 4) {
        float4 av0 = *(const float4*)(sA + (rbase + 0) * 132 + kb);
        float4 av1 = *(const float4*)(sA + (rbase + 1) * 132 + kb);
        float4 av2 = *(const float4*)(sA + (rbase + 2) * 132 + kb);
        float4 av3 = *(const float4*)(sA + (rbase + 3) * 132 + kb);
        const float* a0f = (const float*)&av0;
        const float* a1f = (const float*)&av1;
        const float* a2f = (const float*)&av2;
        const float* a3f = (const float*)&av3;
#pragma unroll
        for (int j = 0; j < 4; j++) {
            const float* Wrow = W + (size_t)(kb + j) * 128;
            float w[8];
            *(float4*)(w)     = *(const float4*)(Wrow + cb);
            *(float4*)(w + 4) = *(const float4*)(Wrow + cb + 4);
            float aj0 = a0f[j], aj1 = a1f[j], aj2 = a2f[j], aj3 = a3f[j];
#pragma unroll
            for (int c = 0; c < 8; c++) {
                acc[0][c] += aj0 * w[c];
                acc[1][c] += aj1 * w[c];
                acc[2][c] += aj2 * w[c];
                acc[3][c] += aj3 * w[c];
            }
        }
    }

#pragma unroll
    for (int r = 0; r < 4; r++) {
        int gn = n0 + rbase + r;
        if (gn < N) {
            *(float4*)(C + (size_t)gn * 128 + cb)     = make_float4(acc[r][0], acc[r][1], acc[r][2], acc[r][3]);
            *(float4*)(C + (size_t)gn * 128 + cb + 4) = make_float4(acc[r][4], acc[r][5], acc[r][6], acc[r][7]);
        }
    }

    if (mode == 0) {
        // attention dots: head h = c8>>2; reduce over the 4 col-groups of h
        const int h = c8 >> 2;
        float sat[8], dat[8];
        *(float4*)(sat)     = *(const float4*)(atts + cb);
        *(float4*)(sat + 4) = *(const float4*)(atts + cb + 4);
        *(float4*)(dat)     = *(const float4*)(attd + cb);
        *(float4*)(dat + 4) = *(const float4*)(attd + cb + 4);
#pragma unroll
        for (int r = 0; r < 4; r++) {
            float s = 0.f, d = 0.f;
#pragma unroll
            for (int c = 0; c < 8; c++) { s += acc[r][c] * sat[c]; d += acc[r][c] * dat[c]; }
            s += __shfl_xor(s, 1); s += __shfl_xor(s, 2);
            d += __shfl_xor(d, 1); d += __shfl_xor(d, 2);
            if ((c8 & 3) == 0) {
                int gn = n0 + rbase + r;
                if (gn < N) { aS[(size_t)gn * 4 + h] = s; aD[(size_t)gn * 4 + h] = d; }
            }
        }
    }
}

// ---------------- CSR build ----------------
__global__ __launch_bounds__(256) void k_count(const int* __restrict__ ei,
                                               int* __restrict__ deg, int E)
{
    int e = blockIdx.x * 256 + threadIdx.x;
    if (e < E) atomicAdd(&deg[ei[E + e]], 1);
}

__global__ __launch_bounds__(1024) void k_scan(const int* __restrict__ deg,
                                               int* __restrict__ offs,
                                               int* __restrict__ cur,
                                               float* __restrict__ dinv, int N)
{
    __shared__ int wsum[16];
    const int tid = threadIdx.x, lane = tid & 63, wid = tid >> 6;
    int carry = 0;
    for (int base = 0; base < N; base += 1024) {
        int i = base + tid;
        int v = (i < N) ? deg[i] : 0;
        int incl = v;
#pragma unroll
        for (int off = 1; off < 64; off <<= 1) {
            int t = __shfl_up(incl, off, 64);
            if (lane >= off) incl += t;
        }
        if (lane == 63) wsum[wid] = incl;
        __syncthreads();
        int prefix = 0, total = 0;
        for (int w = 0; w < 16; w++) {
            int x = wsum[w];
            total += x;
            if (w < wid) prefix += x;
        }
        int excl = carry + prefix + incl - v;
        if (i < N) {
            offs[i] = excl; cur[i] = excl;
            dinv[i] = rsqrtf((float)(v + 1));   // deg incl self loop
        }
        carry += total;
        __syncthreads();
    }
    if (tid == 0) offs[N] = carry;
}

__global__ __launch_bounds__(256) void k_scatter(const int* __restrict__ ei,
                                                 int* __restrict__ cur,
                                                 int* __restrict__ csr, int E)
{
    int e = blockIdx.x * 256 + threadIdx.x;
    if (e < E) {
        int d = ei[E + e];
        int slot = atomicAdd(&cur[d], 1);
        csr[slot] = ei[e];
    }
}

// ---------------- GAT aggregation: 4 nodes / 256-thread block --------------
// Unnormalized softmax: u = exp(leaky(aS[src]+aD[dst])); out = (Σ u·h)/(Σ u).
__global__ __launch_bounds__(256) void k_gat_aggr(
    const float* __restrict__ h, const float* __restrict__ aSg,
    const float* __restrict__ aDg, const int* __restrict__ offs,
    const int* __restrict__ csr, float* __restrict__ raw1, int N)
{
    __shared__ __align__(16) float s_u[4][64][4];   // (u0,u2,u1,u3) per edge
    __shared__ int s_s[4][64];

    const int wid = threadIdx.x >> 6;
    const int lane = threadIdx.x & 63;
    const int n = blockIdx.x * 4 + wid;
    if (n >= N) return;

    const int beg = offs[n];
    const int cnt = offs[n + 1] - beg + 1;          // + self loop
    const float4 ad = *(const float4*)(aDg + (size_t)n * 4);
    const int hA = lane >> 5;
    const int hA2 = hA * 2;

    float t0 = 0.f, t1 = 0.f, t2 = 0.f, t3 = 0.f;
    float acc0 = 0.f, acc1 = 0.f;

    for (int base = 0; base < cnt; base += 64) {
        int idx = base + lane;
        bool valid = idx < cnt;
        int src = n;
        if (valid && idx > 0) src = csr[beg + idx - 1];
        float u0 = 0.f, u1 = 0.f, u2 = 0.f, u3 = 0.f;
        if (valid) {
            float4 as = *(const float4*)(aSg + (size_t)src * 4);
            float l0 = as.x + ad.x; l0 = (l0 > 0.f) ? l0 : NEG_SLOPE * l0;
            float l1 = as.y + ad.y; l1 = (l1 > 0.f) ? l1 : NEG_SLOPE * l1;
            float l2 = as.z + ad.z; l2 = (l2 > 0.f) ? l2 : NEG_SLOPE * l2;
            float l3 = as.w + ad.w; l3 = (l3 > 0.f) ? l3 : NEG_SLOPE * l3;
            u0 = __expf(l0); u1 = __expf(l1); u2 = __expf(l2); u3 = __expf(l3);
        }
        t0 += u0; t1 += u1; t2 += u2; t3 += u3;
        s_s[wid][lane] = src;
        s_u[wid][lane][0] = u0; s_u[wid][lane][1] = u2;
        s_u[wid][lane][2] = u1; s_u[wid][lane][3] = u3;

        int cc = min(64, cnt - base);
        int j = 0;
        for (; j + 4 <= cc; j += 4) {
            int sj0 = s_s[wid][j],     sj1 = s_s[wid][j + 1];
            int sj2 = s_s[wid][j + 2], sj3 = s_s[wid][j + 3];
            float2 u0v = *(const float2*)&s_u[wid][j][hA2];
            float2 u1v = *(const float2*)&s_u[wid][j + 1][hA2];
            float2 u2v = *(const float2*)&s_u[wid][j + 2][hA2];
            float2 u3v = *(const float2*)&s_u[wid][j + 3][hA2];
            const float* p0 = h + (size_t)sj0 * 128;
            const float* p1 = h + (size_t)sj1 * 128;
            const float* p2 = h + (size_t)sj2 * 128;
            const float* p3 = h + (size_t)sj3 * 128;
            float xa0 = p0[lane], xb0 = p0[lane + 64];
            float xa1 = p1[lane], xb1 = p1[lane + 64];
            float xa2 = p2[lane], xb2 = p2[lane + 64];
            float xa3 = p3[lane], xb3 = p3[lane + 64];
            acc0 += u0v.x * xa0; acc1 += u0v.y * xb0;
            acc0 += u1v.x * xa1; acc1 += u1v.y * xb1;
            acc0 += u2v.x * xa2; acc1 += u2v.y * xb2;
            acc0 += u3v.x * xa3; acc1 += u3v.y * xb3;
        }
        for (; j < cc; j++) {
            int sj = s_s[wid][j];
            float2 uv = *(const float2*)&s_u[wid][j][hA2];
            const float* p = h + (size_t)sj * 128;
            acc0 += uv.x * p[lane];
            acc1 += uv.y * p[lane + 64];
        }
    }
#pragma unroll
    for (int msk = 1; msk < 64; msk <<= 1) {
        t0 += __shfl_xor(t0, msk);
        t1 += __shfl_xor(t1, msk);
        t2 += __shfl_xor(t2, msk);
        t3 += __shfl_xor(t3, msk);
    }
    float sA_ = (hA ? t1 : t0) + 1e-16f;
    float sB_ = (hA ? t3 : t2) + 1e-16f;
    raw1[(size_t)n * 128 + lane]      = acc0 / sA_;
    raw1[(size_t)n * 128 + 64 + lane] = acc1 / sB_;
}

// ---------------- GCN aggregation + fused BN2/ELU/gate/fc ------------------
__global__ __launch_bounds__(256) void k_gcn_aggr(
    const float* __restrict__ h2, const int* __restrict__ offs,
    const int* __restrict__ csr, const float* __restrict__ dinv,
    const float* __restrict__ bgcn,
    const float* __restrict__ bn2w, const float* __restrict__ bn2b,
    const float* __restrict__ wgate, const float* __restrict__ bgate,
    const float* __restrict__ wfc,
    float* __restrict__ gate, float* __restrict__ fcdot, int N)
{
    __shared__ float s_w[4][64];
    __shared__ int s_s[4][64];

    const int wid = threadIdx.x >> 6;
    const int lane = threadIdx.x & 63;
    const int n = blockIdx.x * 4 + wid;
    if (n >= N) return;

    const int beg = offs[n];
    const int cnt = offs[n + 1] - beg + 1;
    const float dn = dinv[n];

    float acc0 = 0.f, acc1 = 0.f;
    for (int base = 0; base < cnt; base += 64) {
        int idx = base + lane;
        bool valid = idx < cnt;
        int src = n;
        float w = dn * dn;
        if (valid && idx > 0) {
            src = csr[beg + idx - 1];
            w = dinv[src] * dn;
        }
        s_s[wid][lane] = src;
        s_w[wid][lane] = valid ? w : 0.f;

        int cc = min(64, cnt - base);
        int j = 0;
        for (; j + 4 <= cc; j += 4) {
            int sj0 = s_s[wid][j],     sj1 = s_s[wid][j + 1];
            int sj2 = s_s[wid][j + 2], sj3 = s_s[wid][j + 3];
            float w0 = s_w[wid][j],     w1 = s_w[wid][j + 1];
            float w2 = s_w[wid][j + 2], w3 = s_w[wid][j + 3];
            const float* p0 = h2 + (size_t)sj0 * 128;
            const float* p1 = h2 + (size_t)sj1 * 128;
            const float* p2 = h2 + (size_t)sj2 * 128;
            const float* p3 = h2 + (size_t)sj3 * 128;
            float xa0 = p0[lane], xb0 = p0[lane + 64];
            float xa1 = p1[lane], xb1 = p1[lane + 64];
            float xa2 = p2[lane], xb2 = p2[lane + 64];
            float xa3 = p3[lane], xb3 = p3[lane + 64];
            acc0 += w0 * xa0; acc1 += w0 * xb0;
            acc0 += w1 * xa1; acc1 += w1 * xb1;
            acc0 += w2 * xa2; acc1 += w2 * xb2;
            acc0 += w3 * xa3; acc1 += w3 * xb3;
        }
        for (; j < cc; j++) {
            int sj = s_s[wid][j];
            float wj = s_w[wid][j];
            const float* p = h2 + (size_t)sj * 128;
            acc0 += wj * p[lane];
            acc1 += wj * p[lane + 64];
        }
    }
    float v0 = acc0 + bgcn[lane];
    v0 = (v0 > 0.f) ? v0 : expm1f(v0);
    v0 = v0 * bn2w[lane] + bn2b[lane];
    float v1 = acc1 + bgcn[lane + 64];
    v1 = (v1 > 0.f) ? v1 : expm1f(v1);
    v1 = v1 * bn2w[lane + 64] + bn2b[lane + 64];

    float g = v0 * wgate[lane] + v1 * wgate[lane + 64];
    float f = v0 * wfc[lane]   + v1 * wfc[lane + 64];
#pragma unroll
    for (int msk = 1; msk < 64; msk <<= 1) {
        g += __shfl_xor(g, msk);
        f += __shfl_xor(f, msk);
    }
    if (lane == 0) { gate[n] = g + bgate[0]; fcdot[n] = f; }
}

// ---------------- pooling softmax over scalars: one block / graph ----------
__global__ __launch_bounds__(256) void k_pool(
    const float* __restrict__ gate, const float* __restrict__ fcdot,
    const int* __restrict__ batch, const float* __restrict__ bfc,
    float* __restrict__ out, int N)
{
    __shared__ float red[256];
    __shared__ int range[2];
    const int g = blockIdx.x;
    const int tid = threadIdx.x;
    if (tid < 2) range[tid] = lower_bound_i(batch, N, g + tid);
    __syncthreads();
    const int lo = range[0], hi = range[1];
    float se = 0.f, sf = 0.f;
    for (int i = lo + tid; i < hi; i += 256) {
        float e = __expf(gate[i]);
        se += e;
        sf += e * fcdot[i];
    }
    red[tid] = se; __syncthreads();
    for (int s = 128; s > 0; s >>= 1) {
        if (tid < s) red[tid] += red[tid + s];
        __syncthreads();
    }
    se = red[0]; __syncthreads();
    red[tid] = sf; __syncthreads();
    for (int s = 128; s > 0; s >>= 1) {
        if (tid < s) red[tid] += red[tid + s];
        __syncthreads();
    }
    sf = red[0];
    if (tid == 0) out[g] = sf / (se + 1e-16f) + bfc[0];
}

// ---------------------------------------------------------------------------
extern "C" void kernel_launch(void* const* d_in, const int* in_sizes, int n_in,
                              void* d_out, int out_size, void* d_ws, size_t ws_size,
                              hipStream_t stream) {
    const float* x     = (const float*)d_in[0];
    const int*   ei    = (const int*)d_in[1];
    const int*   batch = (const int*)d_in[2];
    const float* Wgat  = (const float*)d_in[3];
    const float* atts  = (const float*)d_in[4];
    const float* attd  = (const float*)d_in[5];
    const float* bgat  = (const float*)d_in[6];
    const float* bn1w  = (const float*)d_in[7];
    const float* bn1b  = (const float*)d_in[8];
    const float* Wgcn  = (const float*)d_in[9];
    const float* bgcn  = (const float*)d_in[10];
    const float* bn2w  = (const float*)d_in[11];
    const float* bn2b  = (const float*)d_in[12];
    const float* wgate = (const float*)d_in[13];
    const float* bgate = (const float*)d_in[14];
    const float* wfc   = (const float*)d_in[15];
    const float* bfc   = (const float*)d_in[16];
    float* out = (float*)d_out;

    const int N = in_sizes[0] / 128;
    const int E = in_sizes[1] / 2;

    float* bufA  = (float*)d_ws;                   // h, then h2      [N*128]
    float* bufB  = bufA + (size_t)N * 128;         // raw1 (GAT out)  [N*128]
    float* aS    = bufB + (size_t)N * 128;         // [N*4]
    float* aD    = aS + (size_t)N * 4;             // [N*4]
    float* gate  = aD + (size_t)N * 4;             // [N]
    float* fcdot = gate + N;                       // [N]
    float* dinv  = fcdot + N;                      // [N]
    int* offs = (int*)(dinv + N);                  // [N+1]
    int* cur  = offs + (N + 1);                    // [N]
    int* csr  = cur + N;                           // [E]
    int* deg  = csr + E;                           // [N]

    hipMemsetAsync(deg, 0, (size_t)N * sizeof(int), stream);

    const int gemm_blocks = (N + 63) / 64;
    const int aggr_blocks = (N + 3) / 4;

    k_count<<<(E + 255) / 256, 256, 0, stream>>>(ei, deg, E);
    k_gemm<<<gemm_blocks, 256, 0, stream>>>(x, Wgat, bufA, N, 0,
                                            nullptr, nullptr, nullptr,
                                            atts, attd, aS, aD);
    k_scan<<<1, 1024, 0, stream>>>(deg, offs, cur, dinv, N);
    k_scatter<<<(E + 255) / 256, 256, 0, stream>>>(ei, cur, csr, E);
    k_gat_aggr<<<aggr_blocks, 256, 0, stream>>>(bufA, aS, aD, offs, csr, bufB, N);
    k_gemm<<<gemm_blocks, 256, 0, stream>>>(bufB, Wgcn, bufA, N, 1,
                                            bgat, bn1w, bn1b,
                                            nullptr, nullptr, nullptr, nullptr);
    k_gcn_aggr<<<aggr_blocks, 256, 0, stream>>>(bufA, offs, csr, dinv, bgcn,
                                                bn2w, bn2b, wgate, bgate, wfc,
                                                gate, fcdot, N);
    k_pool<<<64, 256, 0, stream>>>(gate, fcdot, batch, bfc, out, N);
}

// Round 3
// 408.303 us; speedup vs baseline: 1.4183x; 1.1100x over previous
//
#include <hip/hip_runtime.h>
#include <math.h>

// GoBERT: GATConv(4x32) -> BN -> GCNConv(128) -> BN -> GlobalAttention -> FC
// Round 2: bf16-packed gather tables (halve edge-gather bytes), dinv folded
// into GCN table (unweighted sum), x8-unrolled gathers, 4x faster scan.

#define NEG_SLOPE 0.2f

__device__ __forceinline__ int lower_bound_i(const int* a, int n, int key) {
    int lo = 0, hi = n;
    while (lo < hi) {
        int mid = (lo + hi) >> 1;
        if (a[mid] < key) lo = mid + 1; else hi = mid;
    }
    return lo;
}

// pack two fp32 into bf16 pair (RNE), lo -> low 16 bits
__device__ __forceinline__ unsigned pack_bf16(float lo, float hi) {
    unsigned ua = __float_as_uint(lo);
    unsigned ub = __float_as_uint(hi);
    ua = ua + 0x7fffu + ((ua >> 16) & 1u);
    ub = ub + 0x7fffu + ((ub >> 16) & 1u);
    return (ua >> 16) | (ub & 0xffff0000u);
}

// ---------------- GEMM: Cb[N,64] = pack_bf16( s * f(A)[N,128] @ W ) --------
// mode 0: f = id, s = 1; epilogue computes per-head attention dots aS/aD
// mode 1: f = bn1*elu(a+b_gat)+bn1b, s = dinv[row]  (pre-scaled GCN table)
__global__ __launch_bounds__(256) void k_gemm(
    const float* __restrict__ A, const float* __restrict__ W,
    unsigned* __restrict__ Cb, int N, int mode,
    const float* __restrict__ pb, const float* __restrict__ pw,
    const float* __restrict__ pb2, const float* __restrict__ dinv,
    const float* __restrict__ atts, const float* __restrict__ attd,
    float* __restrict__ aS, float* __restrict__ aD)
{
    __shared__ float sA[64 * 132];
    const int tid = threadIdx.x;
    const int n0 = blockIdx.x * 64;

    for (int i = tid * 4; i < 64 * 128; i += 1024) {
        int r = i >> 7;
        int k = i & 127;
        int gn = n0 + r;
        float4 v = make_float4(0.f, 0.f, 0.f, 0.f);
        if (gn < N) v = *(const float4*)(A + (size_t)gn * 128 + k);
        if (mode) {
            float4 bv = *(const float4*)(pb + k);
            float4 wv = *(const float4*)(pw + k);
            float4 b2 = *(const float4*)(pb2 + k);
            float t;
            t = v.x + bv.x; t = (t > 0.f) ? t : expm1f(t); v.x = t * wv.x + b2.x;
            t = v.y + bv.y; t = (t > 0.f) ? t : expm1f(t); v.y = t * wv.y + b2.y;
            t = v.z + bv.z; t = (t > 0.f) ? t : expm1f(t); v.z = t * wv.z + b2.z;
            t = v.w + bv.w; t = (t > 0.f) ? t : expm1f(t); v.w = t * wv.w + b2.w;
        }
        *(float4*)(sA + r * 132 + k) = v;
    }
    __syncthreads();

    const int c8 = tid & 15;
    const int cb = c8 * 8;
    const int rg = tid >> 4;
    const int rbase = rg * 4;

    float acc[4][8];
#pragma unroll
    for (int r = 0; r < 4; r++)
#pragma unroll
        for (int c = 0; c < 8; c++) acc[r][c] = 0.f;

    for (int kb = 0; kb < 128; kb += 4) {
        float4 av0 = *(const float4*)(sA + (rbase + 0) * 132 + kb);
        float4 av1 = *(const float4*)(sA + (rbase + 1) * 132 + kb);
        float4 av2 = *(const float4*)(sA + (rbase + 2) * 132 + kb);
        float4 av3 = *(const float4*)(sA + (rbase + 3) * 132 + kb);
        const float* a0f = (const float*)&av0;
        const float* a1f = (const float*)&av1;
        const float* a2f = (const float*)&av2;
        const float* a3f = (const float*)&av3;
#pragma unroll
        for (int j = 0; j < 4; j++) {
            const float* Wrow = W + (size_t)(kb + j) * 128;
            float w[8];
            *(float4*)(w)     = *(const float4*)(Wrow + cb);
            *(float4*)(w + 4) = *(const float4*)(Wrow + cb + 4);
            float aj0 = a0f[j], aj1 = a1f[j], aj2 = a2f[j], aj3 = a3f[j];
#pragma unroll
            for (int c = 0; c < 8; c++) {
                acc[0][c] += aj0 * w[c];
                acc[1][c] += aj1 * w[c];
                acc[2][c] += aj2 * w[c];
                acc[3][c] += aj3 * w[c];
            }
        }
    }

#pragma unroll
    for (int r = 0; r < 4; r++) {
        int gn = n0 + rbase + r;
        if (gn < N) {
            float s = mode ? dinv[gn] : 1.f;
            uint4 pv;
            pv.x = pack_bf16(acc[r][0] * s, acc[r][1] * s);
            pv.y = pack_bf16(acc[r][2] * s, acc[r][3] * s);
            pv.z = pack_bf16(acc[r][4] * s, acc[r][5] * s);
            pv.w = pack_bf16(acc[r][6] * s, acc[r][7] * s);
            *(uint4*)(Cb + (size_t)gn * 64 + (cb >> 1)) = pv;
        }
    }

    if (mode == 0) {
        const int h = c8 >> 2;
        float sat[8], dat[8];
        *(float4*)(sat)     = *(const float4*)(atts + cb);
        *(float4*)(sat + 4) = *(const float4*)(atts + cb + 4);
        *(float4*)(dat)     = *(const float4*)(attd + cb);
        *(float4*)(dat + 4) = *(const float4*)(attd + cb + 4);
#pragma unroll
        for (int r = 0; r < 4; r++) {
            float s = 0.f, d = 0.f;
#pragma unroll
            for (int c = 0; c < 8; c++) { s += acc[r][c] * sat[c]; d += acc[r][c] * dat[c]; }
            s += __shfl_xor(s, 1); s += __shfl_xor(s, 2);
            d += __shfl_xor(d, 1); d += __shfl_xor(d, 2);
            if ((c8 & 3) == 0) {
                int gn = n0 + rbase + r;
                if (gn < N) { aS[(size_t)gn * 4 + h] = s; aD[(size_t)gn * 4 + h] = d; }
            }
        }
    }
}

// ---------------- CSR build ----------------
__global__ __launch_bounds__(256) void k_count(const int* __restrict__ ei,
                                               int* __restrict__ deg, int E)
{
    int e = blockIdx.x * 256 + threadIdx.x;
    if (e < E) atomicAdd(&deg[ei[E + e]], 1);
}

__global__ __launch_bounds__(1024) void k_scan(const int* __restrict__ deg,
                                               int* __restrict__ offs,
                                               int* __restrict__ cur,
                                               float* __restrict__ dinv, int N)
{
    __shared__ int wsum[16];
    const int tid = threadIdx.x, lane = tid & 63, wid = tid >> 6;
    int carry = 0;
    for (int base = 0; base < N; base += 4096) {
        int i0 = base + tid * 4;
        int d0 = (i0 + 0 < N) ? deg[i0 + 0] : 0;
        int d1 = (i0 + 1 < N) ? deg[i0 + 1] : 0;
        int d2 = (i0 + 2 < N) ? deg[i0 + 2] : 0;
        int d3 = (i0 + 3 < N) ? deg[i0 + 3] : 0;
        int tot = d0 + d1 + d2 + d3;
        int incl = tot;
#pragma unroll
        for (int off = 1; off < 64; off <<= 1) {
            int t = __shfl_up(incl, off, 64);
            if (lane >= off) incl += t;
        }
        if (lane == 63) wsum[wid] = incl;
        __syncthreads();
        int prefix = 0, total = 0;
        for (int w = 0; w < 16; w++) {
            int x = wsum[w];
            total += x;
            if (w < wid) prefix += x;
        }
        int e = carry + prefix + (incl - tot);
        if (i0 + 0 < N) { offs[i0+0]=e; cur[i0+0]=e; dinv[i0+0]=rsqrtf((float)(d0+1)); } e += d0;
        if (i0 + 1 < N) { offs[i0+1]=e; cur[i0+1]=e; dinv[i0+1]=rsqrtf((float)(d1+1)); } e += d1;
        if (i0 + 2 < N) { offs[i0+2]=e; cur[i0+2]=e; dinv[i0+2]=rsqrtf((float)(d2+1)); } e += d2;
        if (i0 + 3 < N) { offs[i0+3]=e; cur[i0+3]=e; dinv[i0+3]=rsqrtf((float)(d3+1)); }
        carry += total;
        __syncthreads();
    }
    if (tid == 0) offs[N] = carry;
}

__global__ __launch_bounds__(256) void k_scatter(const int* __restrict__ ei,
                                                 int* __restrict__ cur,
                                                 int* __restrict__ csr, int E)
{
    int e = blockIdx.x * 256 + threadIdx.x;
    if (e < E) {
        int d = ei[E + e];
        int slot = atomicAdd(&cur[d], 1);
        csr[slot] = ei[e];
    }
}

// ---------------- GAT aggregation: 4 nodes / 256-thread block --------------
// hb rows are bf16-packed pairs; lane l owns channels 2l,2l+1 (head = l>>4).
__global__ __launch_bounds__(256) void k_gat_aggr(
    const unsigned* __restrict__ hb, const float* __restrict__ aSg,
    const float* __restrict__ aDg, const int* __restrict__ offs,
    const int* __restrict__ csr, float* __restrict__ raw1, int N)
{
    __shared__ __align__(16) float s_u[4][64][4];
    __shared__ int s_s[4][64];

    const int wid = threadIdx.x >> 6;
    const int lane = threadIdx.x & 63;
    const int n = blockIdx.x * 4 + wid;
    if (n >= N) return;

    const int beg = offs[n];
    const int cnt = offs[n + 1] - beg + 1;          // + self loop
    const float4 ad = *(const float4*)(aDg + (size_t)n * 4);
    const int head = lane >> 4;
    const float* pu = &s_u[wid][0][head];
    const int* ps = &s_s[wid][0];

    float t0 = 0.f, t1 = 0.f, t2 = 0.f, t3 = 0.f;
    float accLo = 0.f, accHi = 0.f;

    for (int base = 0; base < cnt; base += 64) {
        int idx = base + lane;
        bool valid = idx < cnt;
        int src = n;
        if (valid && idx > 0) src = csr[beg + idx - 1];
        float u0 = 0.f, u1 = 0.f, u2 = 0.f, u3 = 0.f;
        if (valid) {
            float4 as = *(const float4*)(aSg + (size_t)src * 4);
            float l0 = as.x + ad.x; l0 = (l0 > 0.f) ? l0 : NEG_SLOPE * l0;
            float l1 = as.y + ad.y; l1 = (l1 > 0.f) ? l1 : NEG_SLOPE * l1;
            float l2 = as.z + ad.z; l2 = (l2 > 0.f) ? l2 : NEG_SLOPE * l2;
            float l3 = as.w + ad.w; l3 = (l3 > 0.f) ? l3 : NEG_SLOPE * l3;
            u0 = __expf(l0); u1 = __expf(l1); u2 = __expf(l2); u3 = __expf(l3);
        }
        t0 += u0; t1 += u1; t2 += u2; t3 += u3;
        s_s[wid][lane] = src;
        *(float4*)&s_u[wid][lane][0] = make_float4(u0, u1, u2, u3);

        int cc = min(64, cnt - base);
        int j = 0;
        for (; j + 8 <= cc; j += 8) {
            int sj[8]; float uj[8]; unsigned vv[8];
#pragma unroll
            for (int k = 0; k < 8; k++) sj[k] = ps[j + k];
#pragma unroll
            for (int k = 0; k < 8; k++) uj[k] = pu[(j + k) * 4];
#pragma unroll
            for (int k = 0; k < 8; k++) vv[k] = hb[sj[k] * 64 + lane];
#pragma unroll
            for (int k = 0; k < 8; k++) {
                float lo = __uint_as_float(vv[k] << 16);
                float hi = __uint_as_float(vv[k] & 0xffff0000u);
                accLo += uj[k] * lo;
                accHi += uj[k] * hi;
            }
        }
        for (; j < cc; j++) {
            int sj = ps[j];
            float uj = pu[j * 4];
            unsigned v = hb[sj * 64 + lane];
            accLo += uj * __uint_as_float(v << 16);
            accHi += uj * __uint_as_float(v & 0xffff0000u);
        }
    }
#pragma unroll
    for (int msk = 1; msk < 64; msk <<= 1) {
        t0 += __shfl_xor(t0, msk);
        t1 += __shfl_xor(t1, msk);
        t2 += __shfl_xor(t2, msk);
        t3 += __shfl_xor(t3, msk);
    }
    float s = (head == 0) ? t0 : (head == 1) ? t1 : (head == 2) ? t2 : t3;
    float inv = 1.f / (s + 1e-16f);
    *(float2*)(raw1 + (size_t)n * 128 + 2 * lane) = make_float2(accLo * inv, accHi * inv);
}

// ---------------- GCN aggregation + fused BN2/ELU/gate/fc ------------------
// h2b rows are bf16 pairs pre-scaled by dinv[src]; out2 = dinv[n]*sum + bias.
__global__ __launch_bounds__(256) void k_gcn_aggr(
    const unsigned* __restrict__ h2b, const int* __restrict__ offs,
    const int* __restrict__ csr, const float* __restrict__ dinv,
    const float* __restrict__ bgcn,
    const float* __restrict__ bn2w, const float* __restrict__ bn2b,
    const float* __restrict__ wgate, const float* __restrict__ bgate,
    const float* __restrict__ wfc,
    float* __restrict__ gate, float* __restrict__ fcdot, int N)
{
    __shared__ int s_s[4][64];

    const int wid = threadIdx.x >> 6;
    const int lane = threadIdx.x & 63;
    const int n = blockIdx.x * 4 + wid;
    if (n >= N) return;

    const int beg = offs[n];
    const int cnt = offs[n + 1] - beg + 1;
    const float dn = dinv[n];
    const int* ps = &s_s[wid][0];

    float accLo = 0.f, accHi = 0.f;
    for (int base = 0; base < cnt; base += 64) {
        int idx = base + lane;
        int src = n;
        if (idx > 0 && idx < cnt) src = csr[beg + idx - 1];
        s_s[wid][lane] = src;

        int cc = min(64, cnt - base);
        int j = 0;
        for (; j + 8 <= cc; j += 8) {
            int sj[8]; unsigned vv[8];
#pragma unroll
            for (int k = 0; k < 8; k++) sj[k] = ps[j + k];
#pragma unroll
            for (int k = 0; k < 8; k++) vv[k] = h2b[sj[k] * 64 + lane];
#pragma unroll
            for (int k = 0; k < 8; k++) {
                accLo += __uint_as_float(vv[k] << 16);
                accHi += __uint_as_float(vv[k] & 0xffff0000u);
            }
        }
        for (; j < cc; j++) {
            unsigned v = h2b[ps[j] * 64 + lane];
            accLo += __uint_as_float(v << 16);
            accHi += __uint_as_float(v & 0xffff0000u);
        }
    }
    const int c0 = 2 * lane;
    float v0 = dn * accLo + bgcn[c0];
    v0 = (v0 > 0.f) ? v0 : expm1f(v0);
    v0 = v0 * bn2w[c0] + bn2b[c0];
    float v1 = dn * accHi + bgcn[c0 + 1];
    v1 = (v1 > 0.f) ? v1 : expm1f(v1);
    v1 = v1 * bn2w[c0 + 1] + bn2b[c0 + 1];

    float g = v0 * wgate[c0] + v1 * wgate[c0 + 1];
    float f = v0 * wfc[c0]   + v1 * wfc[c0 + 1];
#pragma unroll
    for (int msk = 1; msk < 64; msk <<= 1) {
        g += __shfl_xor(g, msk);
        f += __shfl_xor(f, msk);
    }
    if (lane == 0) { gate[n] = g + bgate[0]; fcdot[n] = f; }
}

// ---------------- pooling softmax over scalars: one block / graph ----------
__global__ __launch_bounds__(256) void k_pool(
    const float* __restrict__ gate, const float* __restrict__ fcdot,
    const int* __restrict__ batch, const float* __restrict__ bfc,
    float* __restrict__ out, int N)
{
    __shared__ float red[256];
    __shared__ int range[2];
    const int g = blockIdx.x;
    const int tid = threadIdx.x;
    if (tid < 2) range[tid] = lower_bound_i(batch, N, g + tid);
    __syncthreads();
    const int lo = range[0], hi = range[1];
    float se = 0.f, sf = 0.f;
    for (int i = lo + tid; i < hi; i += 256) {
        float e = __expf(gate[i]);
        se += e;
        sf += e * fcdot[i];
    }
    red[tid] = se; __syncthreads();
    for (int s = 128; s > 0; s >>= 1) {
        if (tid < s) red[tid] += red[tid + s];
        __syncthreads();
    }
    se = red[0]; __syncthreads();
    red[tid] = sf; __syncthreads();
    for (int s = 128; s > 0; s >>= 1) {
        if (tid < s) red[tid] += red[tid + s];
        __syncthreads();
    }
    sf = red[0];
    if (tid == 0) out[g] = sf / (se + 1e-16f) + bfc[0];
}

// ---------------------------------------------------------------------------
extern "C" void kernel_launch(void* const* d_in, const int* in_sizes, int n_in,
                              void* d_out, int out_size, void* d_ws, size_t ws_size,
                              hipStream_t stream) {
    const float* x     = (const float*)d_in[0];
    const int*   ei    = (const int*)d_in[1];
    const int*   batch = (const int*)d_in[2];
    const float* Wgat  = (const float*)d_in[3];
    const float* atts  = (const float*)d_in[4];
    const float* attd  = (const float*)d_in[5];
    const float* bgat  = (const float*)d_in[6];
    const float* bn1w  = (const float*)d_in[7];
    const float* bn1b  = (const float*)d_in[8];
    const float* Wgcn  = (const float*)d_in[9];
    const float* bgcn  = (const float*)d_in[10];
    const float* bn2w  = (const float*)d_in[11];
    const float* bn2b  = (const float*)d_in[12];
    const float* wgate = (const float*)d_in[13];
    const float* bgate = (const float*)d_in[14];
    const float* wfc   = (const float*)d_in[15];
    const float* bfc   = (const float*)d_in[16];
    float* out = (float*)d_out;

    const int N = in_sizes[0] / 128;
    const int E = in_sizes[1] / 2;

    unsigned* hb  = (unsigned*)d_ws;               // bf16 h table   [N*64]
    unsigned* h2b = hb + (size_t)N * 64;           // bf16 h2s table [N*64]
    float* raw1  = (float*)(h2b + (size_t)N * 64); // GAT output fp32 [N*128]
    float* aS    = raw1 + (size_t)N * 128;         // [N*4]
    float* aD    = aS + (size_t)N * 4;             // [N*4]
    float* gate  = aD + (size_t)N * 4;             // [N]
    float* fcdot = gate + N;                       // [N]
    float* dinv  = fcdot + N;                      // [N]
    int* offs = (int*)(dinv + N);                  // [N+1]
    int* cur  = offs + (N + 1);                    // [N]
    int* csr  = cur + N;                           // [E]
    int* deg  = csr + E;                           // [N]

    hipMemsetAsync(deg, 0, (size_t)N * sizeof(int), stream);

    const int gemm_blocks = (N + 63) / 64;
    const int aggr_blocks = (N + 3) / 4;

    k_count<<<(E + 255) / 256, 256, 0, stream>>>(ei, deg, E);
    k_gemm<<<gemm_blocks, 256, 0, stream>>>(x, Wgat, hb, N, 0,
                                            nullptr, nullptr, nullptr, nullptr,
                                            atts, attd, aS, aD);
    k_scan<<<1, 1024, 0, stream>>>(deg, offs, cur, dinv, N);
    k_scatter<<<(E + 255) / 256, 256, 0, stream>>>(ei, cur, csr, E);
    k_gat_aggr<<<aggr_blocks, 256, 0, stream>>>(hb, aS, aD, offs, csr, raw1, N);
    k_gemm<<<gemm_blocks, 256, 0, stream>>>(raw1, Wgcn, h2b, N, 1,
                                            bgat, bn1w, bn1b, dinv,
                                            nullptr, nullptr, nullptr, nullptr);
    k_gcn_aggr<<<aggr_blocks, 256, 0, stream>>>(h2b, offs, csr, dinv, bgcn,
                                                bn2w, bn2b, wgate, bgate, wfc,
                                                gate, fcdot, N);
    k_pool<<<64, 256, 0, stream>>>(gate, fcdot, batch, bfc, out, N);
}

// Round 4
// 312.589 us; speedup vs baseline: 1.8526x; 1.3062x over previous
//
#include <hip/hip_runtime.h>
#include <math.h>

// GoBERT: GATConv(4x32) -> BN -> GCNConv(128) -> BN -> GlobalAttention -> FC
// Round 3: CSR build rewritten as two-level bucket sort (bucket = dst>>7).
// Eliminates k_count's 800K global atomics, full-N scan, and the 16x
// write-amplified random scatter (52MB -> ~10MB HBM writes).

#define NEG_SLOPE 0.2f
#define BKT_BITS 7
#define BKT_SIZE 128
#define CHUNK_A 4096

__device__ __forceinline__ int lower_bound_i(const int* a, int n, int key) {
    int lo = 0, hi = n;
    while (lo < hi) {
        int mid = (lo + hi) >> 1;
        if (a[mid] < key) lo = mid + 1; else hi = mid;
    }
    return lo;
}

// pack two fp32 into bf16 pair (RNE), lo -> low 16 bits
__device__ __forceinline__ unsigned pack_bf16(float lo, float hi) {
    unsigned ua = __float_as_uint(lo);
    unsigned ub = __float_as_uint(hi);
    ua = ua + 0x7fffu + ((ua >> 16) & 1u);
    ub = ub + 0x7fffu + ((ub >> 16) & 1u);
    return (ua >> 16) | (ub & 0xffff0000u);
}

// ---------------- GEMM: Cb[N,64] = pack_bf16( s * f(A)[N,128] @ W ) --------
// mode 0: f = id, s = 1; epilogue computes per-head attention dots aS/aD
// mode 1: f = bn1*elu(a+b_gat)+bn1b, s = dinv[row]  (pre-scaled GCN table)
__global__ __launch_bounds__(256) void k_gemm(
    const float* __restrict__ A, const float* __restrict__ W,
    unsigned* __restrict__ Cb, int N, int mode,
    const float* __restrict__ pb, const float* __restrict__ pw,
    const float* __restrict__ pb2, const float* __restrict__ dinv,
    const float* __restrict__ atts, const float* __restrict__ attd,
    float* __restrict__ aS, float* __restrict__ aD)
{
    __shared__ float sA[64 * 132];
    const int tid = threadIdx.x;
    const int n0 = blockIdx.x * 64;

    for (int i = tid * 4; i < 64 * 128; i += 1024) {
        int r = i >> 7;
        int k = i & 127;
        int gn = n0 + r;
        float4 v = make_float4(0.f, 0.f, 0.f, 0.f);
        if (gn < N) v = *(const float4*)(A + (size_t)gn * 128 + k);
        if (mode) {
            float4 bv = *(const float4*)(pb + k);
            float4 wv = *(const float4*)(pw + k);
            float4 b2 = *(const float4*)(pb2 + k);
            float t;
            t = v.x + bv.x; t = (t > 0.f) ? t : expm1f(t); v.x = t * wv.x + b2.x;
            t = v.y + bv.y; t = (t > 0.f) ? t : expm1f(t); v.y = t * wv.y + b2.y;
            t = v.z + bv.z; t = (t > 0.f) ? t : expm1f(t); v.z = t * wv.z + b2.z;
            t = v.w + bv.w; t = (t > 0.f) ? t : expm1f(t); v.w = t * wv.w + b2.w;
        }
        *(float4*)(sA + r * 132 + k) = v;
    }
    __syncthreads();

    const int c8 = tid & 15;
    const int cb = c8 * 8;
    const int rg = tid >> 4;
    const int rbase = rg * 4;

    float acc[4][8];
#pragma unroll
    for (int r = 0; r < 4; r++)
#pragma unroll
        for (int c = 0; c < 8; c++) acc[r][c] = 0.f;

    for (int kb = 0; kb < 128; kb += 4) {
        float4 av0 = *(const float4*)(sA + (rbase + 0) * 132 + kb);
        float4 av1 = *(const float4*)(sA + (rbase + 1) * 132 + kb);
        float4 av2 = *(const float4*)(sA + (rbase + 2) * 132 + kb);
        float4 av3 = *(const float4*)(sA + (rbase + 3) * 132 + kb);
        const float* a0f = (const float*)&av0;
        const float* a1f = (const float*)&av1;
        const float* a2f = (const float*)&av2;
        const float* a3f = (const float*)&av3;
#pragma unroll
        for (int j = 0; j < 4; j++) {
            const float* Wrow = W + (size_t)(kb + j) * 128;
            float w[8];
            *(float4*)(w)     = *(const float4*)(Wrow + cb);
            *(float4*)(w + 4) = *(const float4*)(Wrow + cb + 4);
            float aj0 = a0f[j], aj1 = a1f[j], aj2 = a2f[j], aj3 = a3f[j];
#pragma unroll
            for (int c = 0; c < 8; c++) {
                acc[0][c] += aj0 * w[c];
                acc[1][c] += aj1 * w[c];
                acc[2][c] += aj2 * w[c];
                acc[3][c] += aj3 * w[c];
            }
        }
    }

#pragma unroll
    for (int r = 0; r < 4; r++) {
        int gn = n0 + rbase + r;
        if (gn < N) {
            float s = mode ? dinv[gn] : 1.f;
            uint4 pv;
            pv.x = pack_bf16(acc[r][0] * s, acc[r][1] * s);
            pv.y = pack_bf16(acc[r][2] * s, acc[r][3] * s);
            pv.z = pack_bf16(acc[r][4] * s, acc[r][5] * s);
            pv.w = pack_bf16(acc[r][6] * s, acc[r][7] * s);
            *(uint4*)(Cb + (size_t)gn * 64 + (cb >> 1)) = pv;
        }
    }

    if (mode == 0) {
        const int h = c8 >> 2;
        float sat[8], dat[8];
        *(float4*)(sat)     = *(const float4*)(atts + cb);
        *(float4*)(sat + 4) = *(const float4*)(atts + cb + 4);
        *(float4*)(dat)     = *(const float4*)(attd + cb);
        *(float4*)(dat + 4) = *(const float4*)(attd + cb + 4);
#pragma unroll
        for (int r = 0; r < 4; r++) {
            float s = 0.f, d = 0.f;
#pragma unroll
            for (int c = 0; c < 8; c++) { s += acc[r][c] * sat[c]; d += acc[r][c] * dat[c]; }
            s += __shfl_xor(s, 1); s += __shfl_xor(s, 2);
            d += __shfl_xor(d, 1); d += __shfl_xor(d, 2);
            if ((c8 & 3) == 0) {
                int gn = n0 + rbase + r;
                if (gn < N) { aS[(size_t)gn * 4 + h] = s; aD[(size_t)gn * 4 + h] = d; }
            }
        }
    }
}

// ---------------- CSR build: two-level bucket sort -------------------------
// Pass 1: per-WG LDS histogram of buckets (dst>>7) -> few global atomics.
__global__ __launch_bounds__(256) void k_bhist(const int* __restrict__ dst,
                                               int* __restrict__ bcount,
                                               int E, int NB)
{
    __shared__ int h[512];
    const int tid = threadIdx.x;
    for (int i = tid; i < NB; i += 256) h[i] = 0;
    __syncthreads();
    int base = blockIdx.x * 2048;
#pragma unroll
    for (int k = 0; k < 8; k++) {
        int e = base + k * 256 + tid;
        if (e < E) atomicAdd(&h[dst[e] >> BKT_BITS], 1);
    }
    __syncthreads();
    for (int i = tid; i < NB; i += 256) {
        int c = h[i];
        if (c) atomicAdd(&bcount[i], c);
    }
}

// Pass 2: exclusive scan of bucket counts (single WG, 512 threads).
__global__ __launch_bounds__(512) void k_bscan(const int* __restrict__ bcount,
                                               int* __restrict__ bb,
                                               int* __restrict__ bcur, int NB)
{
    __shared__ int sc[512];
    const int tid = threadIdx.x;
    int own = (tid < NB) ? bcount[tid] : 0;
    sc[tid] = own;
    __syncthreads();
    for (int st = 1; st < 512; st <<= 1) {
        int v = 0;
        if (tid >= st) v = sc[tid - st];
        __syncthreads();
        if (tid >= st) sc[tid] += v;
        __syncthreads();
    }
    int excl = sc[tid] - own;
    if (tid < NB) { bb[tid] = excl; bcur[tid] = excl; }
    if (tid == 511) { bb[NB] = sc[511]; bcur[NB] = sc[511]; }  // = E
}

// Pass 3: scatter (src,dst) pairs into bucket-contiguous storage.
__global__ __launch_bounds__(256) void k_binA(const int* __restrict__ ei,
                                              int* __restrict__ bcur,
                                              int2* __restrict__ pairs,
                                              int E, int NB)
{
    __shared__ int h[512];
    __shared__ int base[512];
    const int tid = threadIdx.x;
    for (int i = tid; i < NB + 1; i += 256) h[i] = 0;
    __syncthreads();
    const int c0 = blockIdx.x * CHUNK_A;
    int s[16], d[16], b[16];
#pragma unroll
    for (int k = 0; k < 16; k++) {
        int e = c0 + k * 256 + tid;
        bool v = e < E;
        s[k] = v ? ei[e] : 0;
        d[k] = v ? ei[E + e] : 0;
        b[k] = v ? (d[k] >> BKT_BITS) : NB;        // sentinel bucket
        atomicAdd(&h[b[k]], 1);
    }
    __syncthreads();
    for (int i = tid; i < NB + 1; i += 256) {
        int c = h[i];
        base[i] = c ? atomicAdd(&bcur[i], c) : 0;
        h[i] = 0;
    }
    __syncthreads();
#pragma unroll
    for (int k = 0; k < 16; k++) {
        int r = atomicAdd(&h[b[k]], 1);
        pairs[base[b[k]] + r] = make_int2(s[k], d[k]);
    }
}

// Pass 4: one WG per bucket: per-dst hist + scan -> offs/dinv, then dense
// in-window CSR scatter (single writer WG per cache line).
__global__ __launch_bounds__(256) void k_binB(const int2* __restrict__ pairs,
                                              const int* __restrict__ bb,
                                              int* __restrict__ csr,
                                              int* __restrict__ offs,
                                              float* __restrict__ dinv,
                                              int N, int NB, int E)
{
    __shared__ int hist[BKT_SIZE], start[BKT_SIZE], cur[BKT_SIZE];
    __shared__ int sc[BKT_SIZE];
    const int tid = threadIdx.x;
    const int b = blockIdx.x;
    const int d0 = b << BKT_BITS;
    const int pbg = bb[b], peg = bb[b + 1];

    if (tid < BKT_SIZE) { hist[tid] = 0; cur[tid] = 0; }
    __syncthreads();
    for (int i = pbg + tid; i < peg; i += 256)
        atomicAdd(&hist[pairs[i].y - d0], 1);
    __syncthreads();
    int own = (tid < BKT_SIZE) ? hist[tid] : 0;
    if (tid < BKT_SIZE) sc[tid] = own;
    __syncthreads();
    for (int st = 1; st < BKT_SIZE; st <<= 1) {
        int v = 0;
        bool act = (tid < BKT_SIZE) && (tid >= st);
        if (act) v = sc[tid - st];
        __syncthreads();
        if (act) sc[tid] += v;
        __syncthreads();
    }
    if (tid < BKT_SIZE) {
        int abs0 = pbg + (sc[tid] - own);
        start[tid] = abs0;
        int d = d0 + tid;
        if (d < N) {
            offs[d] = abs0;
            dinv[d] = rsqrtf((float)(own + 1));
        }
    }
    if (tid == 0 && b == NB - 1) offs[N] = E;
    __syncthreads();
    for (int i = pbg + tid; i < peg; i += 256) {
        int2 p = pairs[i];
        int ld = p.y - d0;
        int r = atomicAdd(&cur[ld], 1);
        csr[start[ld] + r] = p.x;
    }
}

// ---------------- GAT aggregation: 4 nodes / 256-thread block --------------
__global__ __launch_bounds__(256) void k_gat_aggr(
    const unsigned* __restrict__ hb, const float* __restrict__ aSg,
    const float* __restrict__ aDg, const int* __restrict__ offs,
    const int* __restrict__ csr, float* __restrict__ raw1, int N)
{
    __shared__ __align__(16) float s_u[4][64][4];
    __shared__ int s_s[4][64];

    const int wid = threadIdx.x >> 6;
    const int lane = threadIdx.x & 63;
    const int n = blockIdx.x * 4 + wid;
    if (n >= N) return;

    const int beg = offs[n];
    const int cnt = offs[n + 1] - beg + 1;          // + self loop
    const float4 ad = *(const float4*)(aDg + (size_t)n * 4);
    const int head = lane >> 4;
    const float* pu = &s_u[wid][0][head];
    const int* ps = &s_s[wid][0];

    float t0 = 0.f, t1 = 0.f, t2 = 0.f, t3 = 0.f;
    float accLo = 0.f, accHi = 0.f;

    for (int base = 0; base < cnt; base += 64) {
        int idx = base + lane;
        bool valid = idx < cnt;
        int src = n;
        if (valid && idx > 0) src = csr[beg + idx - 1];
        float u0 = 0.f, u1 = 0.f, u2 = 0.f, u3 = 0.f;
        if (valid) {
            float4 as = *(const float4*)(aSg + (size_t)src * 4);
            float l0 = as.x + ad.x; l0 = (l0 > 0.f) ? l0 : NEG_SLOPE * l0;
            float l1 = as.y + ad.y; l1 = (l1 > 0.f) ? l1 : NEG_SLOPE * l1;
            float l2 = as.z + ad.z; l2 = (l2 > 0.f) ? l2 : NEG_SLOPE * l2;
            float l3 = as.w + ad.w; l3 = (l3 > 0.f) ? l3 : NEG_SLOPE * l3;
            u0 = __expf(l0); u1 = __expf(l1); u2 = __expf(l2); u3 = __expf(l3);
        }
        t0 += u0; t1 += u1; t2 += u2; t3 += u3;
        s_s[wid][lane] = src;
        *(float4*)&s_u[wid][lane][0] = make_float4(u0, u1, u2, u3);

        int cc = min(64, cnt - base);
        int j = 0;
        for (; j + 8 <= cc; j += 8) {
            int sj[8]; float uj[8]; unsigned vv[8];
#pragma unroll
            for (int k = 0; k < 8; k++) sj[k] = ps[j + k];
#pragma unroll
            for (int k = 0; k < 8; k++) uj[k] = pu[(j + k) * 4];
#pragma unroll
            for (int k = 0; k < 8; k++) vv[k] = hb[sj[k] * 64 + lane];
#pragma unroll
            for (int k = 0; k < 8; k++) {
                float lo = __uint_as_float(vv[k] << 16);
                float hi = __uint_as_float(vv[k] & 0xffff0000u);
                accLo += uj[k] * lo;
                accHi += uj[k] * hi;
            }
        }
        for (; j < cc; j++) {
            int sj = ps[j];
            float uj = pu[j * 4];
            unsigned v = hb[sj * 64 + lane];
            accLo += uj * __uint_as_float(v << 16);
            accHi += uj * __uint_as_float(v & 0xffff0000u);
        }
    }
#pragma unroll
    for (int msk = 1; msk < 64; msk <<= 1) {
        t0 += __shfl_xor(t0, msk);
        t1 += __shfl_xor(t1, msk);
        t2 += __shfl_xor(t2, msk);
        t3 += __shfl_xor(t3, msk);
    }
    float s = (head == 0) ? t0 : (head == 1) ? t1 : (head == 2) ? t2 : t3;
    float inv = 1.f / (s + 1e-16f);
    *(float2*)(raw1 + (size_t)n * 128 + 2 * lane) = make_float2(accLo * inv, accHi * inv);
}

// ---------------- GCN aggregation + fused BN2/ELU/gate/fc ------------------
__global__ __launch_bounds__(256) void k_gcn_aggr(
    const unsigned* __restrict__ h2b, const int* __restrict__ offs,
    const int* __restrict__ csr, const float* __restrict__ dinv,
    const float* __restrict__ bgcn,
    const float* __restrict__ bn2w, const float* __restrict__ bn2b,
    const float* __restrict__ wgate, const float* __restrict__ bgate,
    const float* __restrict__ wfc,
    float* __restrict__ gate, float* __restrict__ fcdot, int N)
{
    __shared__ int s_s[4][64];

    const int wid = threadIdx.x >> 6;
    const int lane = threadIdx.x & 63;
    const int n = blockIdx.x * 4 + wid;
    if (n >= N) return;

    const int beg = offs[n];
    const int cnt = offs[n + 1] - beg + 1;
    const float dn = dinv[n];
    const int* ps = &s_s[wid][0];

    float accLo = 0.f, accHi = 0.f;
    for (int base = 0; base < cnt; base += 64) {
        int idx = base + lane;
        int src = n;
        if (idx > 0 && idx < cnt) src = csr[beg + idx - 1];
        s_s[wid][lane] = src;

        int cc = min(64, cnt - base);
        int j = 0;
        for (; j + 8 <= cc; j += 8) {
            int sj[8]; unsigned vv[8];
#pragma unroll
            for (int k = 0; k < 8; k++) sj[k] = ps[j + k];
#pragma unroll
            for (int k = 0; k < 8; k++) vv[k] = h2b[sj[k] * 64 + lane];
#pragma unroll
            for (int k = 0; k < 8; k++) {
                accLo += __uint_as_float(vv[k] << 16);
                accHi += __uint_as_float(vv[k] & 0xffff0000u);
            }
        }
        for (; j < cc; j++) {
            unsigned v = h2b[ps[j] * 64 + lane];
            accLo += __uint_as_float(v << 16);
            accHi += __uint_as_float(v & 0xffff0000u);
        }
    }
    const int c0 = 2 * lane;
    float v0 = dn * accLo + bgcn[c0];
    v0 = (v0 > 0.f) ? v0 : expm1f(v0);
    v0 = v0 * bn2w[c0] + bn2b[c0];
    float v1 = dn * accHi + bgcn[c0 + 1];
    v1 = (v1 > 0.f) ? v1 : expm1f(v1);
    v1 = v1 * bn2w[c0 + 1] + bn2b[c0 + 1];

    float g = v0 * wgate[c0] + v1 * wgate[c0 + 1];
    float f = v0 * wfc[c0]   + v1 * wfc[c0 + 1];
#pragma unroll
    for (int msk = 1; msk < 64; msk <<= 1) {
        g += __shfl_xor(g, msk);
        f += __shfl_xor(f, msk);
    }
    if (lane == 0) { gate[n] = g + bgate[0]; fcdot[n] = f; }
}

// ---------------- pooling softmax over scalars: one block / graph ----------
__global__ __launch_bounds__(256) void k_pool(
    const float* __restrict__ gate, const float* __restrict__ fcdot,
    const int* __restrict__ batch, const float* __restrict__ bfc,
    float* __restrict__ out, int N)
{
    __shared__ float red[256];
    __shared__ int range[2];
    const int g = blockIdx.x;
    const int tid = threadIdx.x;
    if (tid < 2) range[tid] = lower_bound_i(batch, N, g + tid);
    __syncthreads();
    const int lo = range[0], hi = range[1];
    float se = 0.f, sf = 0.f;
    for (int i = lo + tid; i < hi; i += 256) {
        float e = __expf(gate[i]);
        se += e;
        sf += e * fcdot[i];
    }
    red[tid] = se; __syncthreads();
    for (int s = 128; s > 0; s >>= 1) {
        if (tid < s) red[tid] += red[tid + s];
        __syncthreads();
    }
    se = red[0]; __syncthreads();
    red[tid] = sf; __syncthreads();
    for (int s = 128; s > 0; s >>= 1) {
        if (tid < s) red[tid] += red[tid + s];
        __syncthreads();
    }
    sf = red[0];
    if (tid == 0) out[g] = sf / (se + 1e-16f) + bfc[0];
}

// ---------------------------------------------------------------------------
extern "C" void kernel_launch(void* const* d_in, const int* in_sizes, int n_in,
                              void* d_out, int out_size, void* d_ws, size_t ws_size,
                              hipStream_t stream) {
    const float* x     = (const float*)d_in[0];
    const int*   ei    = (const int*)d_in[1];
    const int*   batch = (const int*)d_in[2];
    const float* Wgat  = (const float*)d_in[3];
    const float* atts  = (const float*)d_in[4];
    const float* attd  = (const float*)d_in[5];
    const float* bgat  = (const float*)d_in[6];
    const float* bn1w  = (const float*)d_in[7];
    const float* bn1b  = (const float*)d_in[8];
    const float* Wgcn  = (const float*)d_in[9];
    const float* bgcn  = (const float*)d_in[10];
    const float* bn2w  = (const float*)d_in[11];
    const float* bn2b  = (const float*)d_in[12];
    const float* wgate = (const float*)d_in[13];
    const float* bgate = (const float*)d_in[14];
    const float* wfc   = (const float*)d_in[15];
    const float* bfc   = (const float*)d_in[16];
    float* out = (float*)d_out;

    const int N = in_sizes[0] / 128;
    const int E = in_sizes[1] / 2;
    const int NB = (N + BKT_SIZE - 1) / BKT_SIZE;   // buckets of 128 dsts

    unsigned* hb  = (unsigned*)d_ws;               // bf16 h table   [N*64]
    unsigned* h2b = hb + (size_t)N * 64;           // bf16 h2s table [N*64]
    float* raw1  = (float*)(h2b + (size_t)N * 64); // GAT out fp32 [N*128]
    int2* pairs  = (int2*)raw1;                    // aliased: used pre-gat only
    float* aS    = raw1 + (size_t)N * 128;         // [N*4]
    float* aD    = aS + (size_t)N * 4;             // [N*4]
    float* gate  = aD + (size_t)N * 4;             // [N]
    float* fcdot = gate + N;                       // [N]
    float* dinv  = fcdot + N;                      // [N]
    int* offs   = (int*)(dinv + N);                // [N+1]
    int* csr    = offs + (N + 1);                  // [E]
    int* bcount = csr + E;                         // [NB+1]
    int* bb     = bcount + (NB + 1);               // [NB+1]
    int* bcur   = bb + (NB + 1);                   // [NB+1]

    hipMemsetAsync(bcount, 0, (size_t)(NB + 1) * sizeof(int), stream);

    const int gemm_blocks = (N + 63) / 64;
    const int aggr_blocks = (N + 3) / 4;

    k_gemm<<<gemm_blocks, 256, 0, stream>>>(x, Wgat, hb, N, 0,
                                            nullptr, nullptr, nullptr, nullptr,
                                            atts, attd, aS, aD);
    k_bhist<<<(E + 2047) / 2048, 256, 0, stream>>>(ei + E, bcount, E, NB);
    k_bscan<<<1, 512, 0, stream>>>(bcount, bb, bcur, NB);
    k_binA<<<(E + CHUNK_A - 1) / CHUNK_A, 256, 0, stream>>>(ei, bcur, pairs, E, NB);
    k_binB<<<NB, 256, 0, stream>>>(pairs, bb, csr, offs, dinv, N, NB, E);
    k_gat_aggr<<<aggr_blocks, 256, 0, stream>>>(hb, aS, aD, offs, csr, raw1, N);
    k_gemm<<<gemm_blocks, 256, 0, stream>>>(raw1, Wgcn, h2b, N, 1,
                                            bgat, bn1w, bn1b, dinv,
                                            nullptr, nullptr, nullptr, nullptr);
    k_gcn_aggr<<<aggr_blocks, 256, 0, stream>>>(h2b, offs, csr, dinv, bgcn,
                                                bn2w, bn2b, wgate, bgate, wfc,
                                                gate, fcdot, N);
    k_pool<<<64, 256, 0, stream>>>(gate, fcdot, batch, bfc, out, N);
}

// Round 5
// 276.689 us; speedup vs baseline: 2.0929x; 1.1297x over previous
//
#include <hip/hip_runtime.h>
#include <math.h>

// GoBERT: GATConv(4x32) -> BN -> GCNConv(128) -> BN -> GlobalAttention -> FC
// Round 4: MFMA bf16 GEMMs. W transposed+bf16 once (k_prep); attention dots
// folded in as 8 extra GEMM columns (aS = x @ (W@att_src) exactly). Gather
// tables switch to (c, c+64) channel pairing to match MFMA D-layout packing.

#define NEG_SLOPE 0.2f
#define BKT_BITS 7
#define BKT_SIZE 128
#define CHUNK_A 4096

typedef __attribute__((ext_vector_type(8))) short short8v;
typedef __attribute__((ext_vector_type(4))) float floatx4;

__device__ __forceinline__ int lower_bound_i(const int* a, int n, int key) {
    int lo = 0, hi = n;
    while (lo < hi) {
        int mid = (lo + hi) >> 1;
        if (a[mid] < key) lo = mid + 1; else hi = mid;
    }
    return lo;
}

__device__ __forceinline__ unsigned pack_bf16(float lo, float hi) {
    unsigned ua = __float_as_uint(lo);
    unsigned ub = __float_as_uint(hi);
    ua = ua + 0x7fffu + ((ua >> 16) & 1u);
    ub = ub + 0x7fffu + ((ub >> 16) & 1u);
    return (ua >> 16) | (ub & 0xffff0000u);
}

__device__ __forceinline__ unsigned short bf16_1(float v) {
    unsigned u = __float_as_uint(v);
    u = u + 0x7fffu + ((u >> 16) & 1u);
    return (unsigned short)(u >> 16);
}

// ---------------- prep: transposed bf16 weights ----------------------------
// Wt1[144][128]: rows 0-127 = W_gat cols; 128-131 = W@att_src; 132-135 =
// W@att_dst; 136-143 = 0.  Wt2[144][128]: W_gcn cols, rows>=128 zero.
__global__ __launch_bounds__(1024) void k_prep(
    const float* __restrict__ W1, const float* __restrict__ atts,
    const float* __restrict__ attd, const float* __restrict__ W2,
    unsigned short* __restrict__ Wt1, unsigned short* __restrict__ Wt2)
{
    if (blockIdx.x == 0) {
        for (int idx = threadIdx.x; idx < 144 * 128; idx += 1024) {
            int j = idx >> 7, i = idx & 127;
            float v;
            if (j < 128) v = W1[i * 128 + j];
            else if (j < 132) {
                int h = j - 128; float s = 0.f;
                for (int c = 0; c < 32; c++) s += W1[i * 128 + h * 32 + c] * atts[h * 32 + c];
                v = s;
            } else if (j < 136) {
                int h = j - 132; float s = 0.f;
                for (int c = 0; c < 32; c++) s += W1[i * 128 + h * 32 + c] * attd[h * 32 + c];
                v = s;
            } else v = 0.f;
            Wt1[idx] = bf16_1(v);
        }
    } else {
        for (int idx = threadIdx.x; idx < 144 * 128; idx += 1024) {
            int j = idx >> 7, i = idx & 127;
            Wt2[idx] = bf16_1(j < 128 ? W2[i * 128 + j] : 0.f);
        }
    }
}

// ---------------- MFMA GEMM: Cb[N,64 pairs] = pack( s*f(A) @ W ) -----------
// Pair t of row n = channels (t, t+64). mode 0: aS/aD from cols 128-135.
// mode 1: f = bn1*elu(a+b_gat)+bn1b, s = dinv[row].
__global__ __launch_bounds__(256) void k_gemm_mfma(
    const float* __restrict__ A, const unsigned short* __restrict__ Wt,
    unsigned* __restrict__ Cb, int N, int mode,
    const float* __restrict__ pb, const float* __restrict__ pw,
    const float* __restrict__ pb2, const float* __restrict__ dinv,
    float* __restrict__ aS, float* __restrict__ aD)
{
    __shared__ unsigned short sA[64 * 136];
    __shared__ unsigned short sB[144 * 136];
    const int tid = threadIdx.x;
    const int n0 = blockIdx.x * 64;

    // stage B: linear coalesced copy, LDS stride 136
    {
        const uint4* Wg = (const uint4*)Wt;
#pragma unroll
        for (int i = 0; i < 9; i++) {
            int q = tid + 256 * i;              // uint4 index; 144*16 = 2304
            uint4 v = Wg[q];
            int j = q >> 4, seg = q & 15;
            *(uint4*)(sB + j * 136 + seg * 8) = v;
        }
    }
    // stage A: float4-linear coalesced, convert to bf16 (fused transform)
    {
#pragma unroll
        for (int i = 0; i < 8; i++) {
            int g = tid + 256 * i;              // float4 index; 64*32 = 2048
            int r = g >> 5, w4 = g & 31;
            int gn = n0 + r;
            unsigned p0 = 0, p1 = 0;
            if (gn < N) {
                float4 v = *(const float4*)(A + (size_t)gn * 128 + w4 * 4);
                if (mode) {
                    int k = w4 * 4;
                    float4 bv = *(const float4*)(pb + k);
                    float4 wv = *(const float4*)(pw + k);
                    float4 b2 = *(const float4*)(pb2 + k);
                    float t;
                    t = v.x + bv.x; t = (t > 0.f) ? t : expm1f(t); v.x = t * wv.x + b2.x;
                    t = v.y + bv.y; t = (t > 0.f) ? t : expm1f(t); v.y = t * wv.y + b2.y;
                    t = v.z + bv.z; t = (t > 0.f) ? t : expm1f(t); v.z = t * wv.z + b2.z;
                    t = v.w + bv.w; t = (t > 0.f) ? t : expm1f(t); v.w = t * wv.w + b2.w;
                }
                p0 = pack_bf16(v.x, v.y);
                p1 = pack_bf16(v.z, v.w);
            }
            uint2 pv = make_uint2(p0, p1);
            *(uint2*)(sA + r * 136 + w4 * 4) = pv;
        }
    }
    __syncthreads();

    const int wid = tid >> 6, lane = tid & 63;
    const int quad = lane >> 4, l16 = lane & 15;

    floatx4 acc[9];
#pragma unroll
    for (int ct = 0; ct < 9; ct++) acc[ct] = (floatx4){0.f, 0.f, 0.f, 0.f};

    const unsigned short* pa = sA + (wid * 16 + l16) * 136 + quad * 8;
    const unsigned short* pbt = sB + l16 * 136 + quad * 8;
#pragma unroll
    for (int ks = 0; ks < 4; ks++) {
        short8v a = *(const short8v*)(pa + ks * 32);
#pragma unroll
        for (int ct = 0; ct < 9; ct++) {
            short8v b = *(const short8v*)(pbt + ct * (16 * 136) + ks * 32);
            acc[ct] = __builtin_amdgcn_mfma_f32_16x16x32_bf16(a, b, acc[ct], 0, 0, 0);
        }
    }

    // epilogue: lane holds rows quad*4+r, cols ct*16+l16
#pragma unroll
    for (int r = 0; r < 4; r++) {
        int n = n0 + wid * 16 + quad * 4 + r;
        if (n >= N) continue;
        float s = mode ? dinv[n] : 1.f;
#pragma unroll
        for (int ct = 0; ct < 4; ct++) {
            Cb[(size_t)n * 64 + ct * 16 + l16] =
                pack_bf16(acc[ct][r] * s, acc[ct + 4][r] * s);
        }
        if (mode == 0) {
            float e = acc[8][r];
            if (l16 < 4) aS[(size_t)n * 4 + l16] = e;
            else if (l16 < 8) aD[(size_t)n * 4 + (l16 - 4)] = e;
        }
    }
}

// ---------------- CSR build: two-level bucket sort -------------------------
__global__ __launch_bounds__(256) void k_bhist(const int* __restrict__ dst,
                                               int* __restrict__ bcount,
                                               int E, int NB)
{
    __shared__ int h[512];
    const int tid = threadIdx.x;
    for (int i = tid; i < NB; i += 256) h[i] = 0;
    __syncthreads();
    int base = blockIdx.x * 2048;
#pragma unroll
    for (int k = 0; k < 8; k++) {
        int e = base + k * 256 + tid;
        if (e < E) atomicAdd(&h[dst[e] >> BKT_BITS], 1);
    }
    __syncthreads();
    for (int i = tid; i < NB; i += 256) {
        int c = h[i];
        if (c) atomicAdd(&bcount[i], c);
    }
}

__global__ __launch_bounds__(512) void k_bscan(const int* __restrict__ bcount,
                                               int* __restrict__ bb,
                                               int* __restrict__ bcur, int NB)
{
    __shared__ int sc[512];
    const int tid = threadIdx.x;
    int own = (tid < NB) ? bcount[tid] : 0;
    sc[tid] = own;
    __syncthreads();
    for (int st = 1; st < 512; st <<= 1) {
        int v = 0;
        if (tid >= st) v = sc[tid - st];
        __syncthreads();
        if (tid >= st) sc[tid] += v;
        __syncthreads();
    }
    int excl = sc[tid] - own;
    if (tid < NB) { bb[tid] = excl; bcur[tid] = excl; }
    if (tid == 511) { bb[NB] = sc[511]; bcur[NB] = sc[511]; }
}

__global__ __launch_bounds__(256) void k_binA(const int* __restrict__ ei,
                                              int* __restrict__ bcur,
                                              int2* __restrict__ pairs,
                                              int E, int NB)
{
    __shared__ int h[512];
    __shared__ int base[512];
    const int tid = threadIdx.x;
    for (int i = tid; i < NB + 1; i += 256) h[i] = 0;
    __syncthreads();
    const int c0 = blockIdx.x * CHUNK_A;
    int s[16], d[16], b[16];
#pragma unroll
    for (int k = 0; k < 16; k++) {
        int e = c0 + k * 256 + tid;
        bool v = e < E;
        s[k] = v ? ei[e] : 0;
        d[k] = v ? ei[E + e] : 0;
        b[k] = v ? (d[k] >> BKT_BITS) : NB;
        atomicAdd(&h[b[k]], 1);
    }
    __syncthreads();
    for (int i = tid; i < NB + 1; i += 256) {
        int c = h[i];
        base[i] = c ? atomicAdd(&bcur[i], c) : 0;
        h[i] = 0;
    }
    __syncthreads();
#pragma unroll
    for (int k = 0; k < 16; k++) {
        int r = atomicAdd(&h[b[k]], 1);
        pairs[base[b[k]] + r] = make_int2(s[k], d[k]);
    }
}

__global__ __launch_bounds__(256) void k_binB(const int2* __restrict__ pairs,
                                              const int* __restrict__ bb,
                                              int* __restrict__ csr,
                                              int* __restrict__ offs,
                                              float* __restrict__ dinv,
                                              int N, int NB, int E)
{
    __shared__ int hist[BKT_SIZE], start[BKT_SIZE], cur[BKT_SIZE];
    __shared__ int sc[BKT_SIZE];
    const int tid = threadIdx.x;
    const int b = blockIdx.x;
    const int d0 = b << BKT_BITS;
    const int pbg = bb[b], peg = bb[b + 1];

    if (tid < BKT_SIZE) { hist[tid] = 0; cur[tid] = 0; }
    __syncthreads();
    for (int i = pbg + tid; i < peg; i += 256)
        atomicAdd(&hist[pairs[i].y - d0], 1);
    __syncthreads();
    int own = (tid < BKT_SIZE) ? hist[tid] : 0;
    if (tid < BKT_SIZE) sc[tid] = own;
    __syncthreads();
    for (int st = 1; st < BKT_SIZE; st <<= 1) {
        int v = 0;
        bool act = (tid < BKT_SIZE) && (tid >= st);
        if (act) v = sc[tid - st];
        __syncthreads();
        if (act) sc[tid] += v;
        __syncthreads();
    }
    if (tid < BKT_SIZE) {
        int abs0 = pbg + (sc[tid] - own);
        start[tid] = abs0;
        int d = d0 + tid;
        if (d < N) {
            offs[d] = abs0;
            dinv[d] = rsqrtf((float)(own + 1));
        }
    }
    if (tid == 0 && b == NB - 1) offs[N] = E;
    __syncthreads();
    for (int i = pbg + tid; i < peg; i += 256) {
        int2 p = pairs[i];
        int ld = p.y - d0;
        int r = atomicAdd(&cur[ld], 1);
        csr[start[ld] + r] = p.x;
    }
}

// ---------------- GAT aggregation: 4 nodes / 256-thread block --------------
// hb pair t = channels (t, t+64); lane l owns (l, l+64); hA = l>>5.
__global__ __launch_bounds__(256) void k_gat_aggr(
    const unsigned* __restrict__ hb, const float* __restrict__ aSg,
    const float* __restrict__ aDg, const int* __restrict__ offs,
    const int* __restrict__ csr, float* __restrict__ raw1, int N)
{
    __shared__ __align__(16) float s_u[4][64][4];   // (u0,u2,u1,u3)
    __shared__ int s_s[4][64];

    const int wid = threadIdx.x >> 6;
    const int lane = threadIdx.x & 63;
    const int n = blockIdx.x * 4 + wid;
    if (n >= N) return;

    const int beg = offs[n];
    const int cnt = offs[n + 1] - beg + 1;          // + self loop
    const float4 ad = *(const float4*)(aDg + (size_t)n * 4);
    const int hA = lane >> 5;
    const float* pu = &s_u[wid][0][2 * hA];
    const int* ps = &s_s[wid][0];

    float t0 = 0.f, t1 = 0.f, t2 = 0.f, t3 = 0.f;
    float accLo = 0.f, accHi = 0.f;

    for (int base = 0; base < cnt; base += 64) {
        int idx = base + lane;
        bool valid = idx < cnt;
        int src = n;
        if (valid && idx > 0) src = csr[beg + idx - 1];
        float u0 = 0.f, u1 = 0.f, u2 = 0.f, u3 = 0.f;
        if (valid) {
            float4 as = *(const float4*)(aSg + (size_t)src * 4);
            float l0 = as.x + ad.x; l0 = (l0 > 0.f) ? l0 : NEG_SLOPE * l0;
            float l1 = as.y + ad.y; l1 = (l1 > 0.f) ? l1 : NEG_SLOPE * l1;
            float l2 = as.z + ad.z; l2 = (l2 > 0.f) ? l2 : NEG_SLOPE * l2;
            float l3 = as.w + ad.w; l3 = (l3 > 0.f) ? l3 : NEG_SLOPE * l3;
            u0 = __expf(l0); u1 = __expf(l1); u2 = __expf(l2); u3 = __expf(l3);
        }
        t0 += u0; t1 += u1; t2 += u2; t3 += u3;
        s_s[wid][lane] = src;
        *(float4*)&s_u[wid][lane][0] = make_float4(u0, u2, u1, u3);

        int cc = min(64, cnt - base);
        int j = 0;
        for (; j + 8 <= cc; j += 8) {
            int sj[8]; float2 uj[8]; unsigned vv[8];
#pragma unroll
            for (int k = 0; k < 8; k++) sj[k] = ps[j + k];
#pragma unroll
            for (int k = 0; k < 8; k++) uj[k] = *(const float2*)&pu[(j + k) * 4];
#pragma unroll
            for (int k = 0; k < 8; k++) vv[k] = hb[sj[k] * 64 + lane];
#pragma unroll
            for (int k = 0; k < 8; k++) {
                float lo = __uint_as_float(vv[k] << 16);
                float hi = __uint_as_float(vv[k] & 0xffff0000u);
                accLo += uj[k].x * lo;
                accHi += uj[k].y * hi;
            }
        }
        for (; j < cc; j++) {
            int sj = ps[j];
            float2 uv = *(const float2*)&pu[j * 4];
            unsigned v = hb[sj * 64 + lane];
            accLo += uv.x * __uint_as_float(v << 16);
            accHi += uv.y * __uint_as_float(v & 0xffff0000u);
        }
    }
#pragma unroll
    for (int msk = 1; msk < 64; msk <<= 1) {
        t0 += __shfl_xor(t0, msk);
        t1 += __shfl_xor(t1, msk);
        t2 += __shfl_xor(t2, msk);
        t3 += __shfl_xor(t3, msk);
    }
    float sLo = (hA ? t1 : t0) + 1e-16f;
    float sHi = (hA ? t3 : t2) + 1e-16f;
    raw1[(size_t)n * 128 + lane]      = accLo / sLo;
    raw1[(size_t)n * 128 + 64 + lane] = accHi / sHi;
}

// ---------------- GCN aggregation + fused BN2/ELU/gate/fc ------------------
__global__ __launch_bounds__(256) void k_gcn_aggr(
    const unsigned* __restrict__ h2b, const int* __restrict__ offs,
    const int* __restrict__ csr, const float* __restrict__ dinv,
    const float* __restrict__ bgcn,
    const float* __restrict__ bn2w, const float* __restrict__ bn2b,
    const float* __restrict__ wgate, const float* __restrict__ bgate,
    const float* __restrict__ wfc,
    float* __restrict__ gate, float* __restrict__ fcdot, int N)
{
    __shared__ int s_s[4][64];

    const int wid = threadIdx.x >> 6;
    const int lane = threadIdx.x & 63;
    const int n = blockIdx.x * 4 + wid;
    if (n >= N) return;

    const int beg = offs[n];
    const int cnt = offs[n + 1] - beg + 1;
    const float dn = dinv[n];
    const int* ps = &s_s[wid][0];

    float accLo = 0.f, accHi = 0.f;
    for (int base = 0; base < cnt; base += 64) {
        int idx = base + lane;
        int src = n;
        if (idx > 0 && idx < cnt) src = csr[beg + idx - 1];
        s_s[wid][lane] = src;

        int cc = min(64, cnt - base);
        int j = 0;
        for (; j + 8 <= cc; j += 8) {
            int sj[8]; unsigned vv[8];
#pragma unroll
            for (int k = 0; k < 8; k++) sj[k] = ps[j + k];
#pragma unroll
            for (int k = 0; k < 8; k++) vv[k] = h2b[sj[k] * 64 + lane];
#pragma unroll
            for (int k = 0; k < 8; k++) {
                accLo += __uint_as_float(vv[k] << 16);
                accHi += __uint_as_float(vv[k] & 0xffff0000u);
            }
        }
        for (; j < cc; j++) {
            unsigned v = h2b[ps[j] * 64 + lane];
            accLo += __uint_as_float(v << 16);
            accHi += __uint_as_float(v & 0xffff0000u);
        }
    }
    float v0 = dn * accLo + bgcn[lane];
    v0 = (v0 > 0.f) ? v0 : expm1f(v0);
    v0 = v0 * bn2w[lane] + bn2b[lane];
    float v1 = dn * accHi + bgcn[lane + 64];
    v1 = (v1 > 0.f) ? v1 : expm1f(v1);
    v1 = v1 * bn2w[lane + 64] + bn2b[lane + 64];

    float g = v0 * wgate[lane] + v1 * wgate[lane + 64];
    float f = v0 * wfc[lane]   + v1 * wfc[lane + 64];
#pragma unroll
    for (int msk = 1; msk < 64; msk <<= 1) {
        g += __shfl_xor(g, msk);
        f += __shfl_xor(f, msk);
    }
    if (lane == 0) { gate[n] = g + bgate[0]; fcdot[n] = f; }
}

// ---------------- pooling softmax over scalars: one block / graph ----------
__global__ __launch_bounds__(256) void k_pool(
    const float* __restrict__ gate, const float* __restrict__ fcdot,
    const int* __restrict__ batch, const float* __restrict__ bfc,
    float* __restrict__ out, int N)
{
    __shared__ float red[256];
    __shared__ int range[2];
    const int g = blockIdx.x;
    const int tid = threadIdx.x;
    if (tid < 2) range[tid] = lower_bound_i(batch, N, g + tid);
    __syncthreads();
    const int lo = range[0], hi = range[1];
    float se = 0.f, sf = 0.f;
    for (int i = lo + tid; i < hi; i += 256) {
        float e = __expf(gate[i]);
        se += e;
        sf += e * fcdot[i];
    }
    red[tid] = se; __syncthreads();
    for (int s = 128; s > 0; s >>= 1) {
        if (tid < s) red[tid] += red[tid + s];
        __syncthreads();
    }
    se = red[0]; __syncthreads();
    red[tid] = sf; __syncthreads();
    for (int s = 128; s > 0; s >>= 1) {
        if (tid < s) red[tid] += red[tid + s];
        __syncthreads();
    }
    sf = red[0];
    if (tid == 0) out[g] = sf / (se + 1e-16f) + bfc[0];
}

// ---------------------------------------------------------------------------
extern "C" void kernel_launch(void* const* d_in, const int* in_sizes, int n_in,
                              void* d_out, int out_size, void* d_ws, size_t ws_size,
                              hipStream_t stream) {
    const float* x     = (const float*)d_in[0];
    const int*   ei    = (const int*)d_in[1];
    const int*   batch = (const int*)d_in[2];
    const float* Wgat  = (const float*)d_in[3];
    const float* atts  = (const float*)d_in[4];
    const float* attd  = (const float*)d_in[5];
    const float* bgat  = (const float*)d_in[6];
    const float* bn1w  = (const float*)d_in[7];
    const float* bn1b  = (const float*)d_in[8];
    const float* Wgcn  = (const float*)d_in[9];
    const float* bgcn  = (const float*)d_in[10];
    const float* bn2w  = (const float*)d_in[11];
    const float* bn2b  = (const float*)d_in[12];
    const float* wgate = (const float*)d_in[13];
    const float* bgate = (const float*)d_in[14];
    const float* wfc   = (const float*)d_in[15];
    const float* bfc   = (const float*)d_in[16];
    float* out = (float*)d_out;

    const int N = in_sizes[0] / 128;
    const int E = in_sizes[1] / 2;
    const int NB = (N + BKT_SIZE - 1) / BKT_SIZE;

    unsigned* hb  = (unsigned*)d_ws;               // bf16 h table   [N*64]
    unsigned* h2b = hb + (size_t)N * 64;           // bf16 h2s table [N*64]
    float* raw1  = (float*)(h2b + (size_t)N * 64); // GAT out fp32 [N*128]
    int2* pairs  = (int2*)raw1;                    // aliased: pre-GAT only
    float* aS    = raw1 + (size_t)N * 128;         // [N*4]
    float* aD    = aS + (size_t)N * 4;             // [N*4]
    float* gate  = aD + (size_t)N * 4;             // [N]
    float* fcdot = gate + N;                       // [N]
    float* dinv  = fcdot + N;                      // [N]
    int* offs   = (int*)(dinv + N);                // [N+1]
    int* csr    = offs + (N + 1);                  // [E]
    int* bcount = csr + E;                         // [NB+1]
    int* bb     = bcount + (NB + 1);               // [NB+1]
    int* bcur   = bb + (NB + 1);                   // [NB+1]
    unsigned short* Wt1 = (unsigned short*)(bcur + (NB + 1)); // [144*128]
    unsigned short* Wt2 = Wt1 + 144 * 128;                    // [144*128]

    hipMemsetAsync(bcount, 0, (size_t)(NB + 1) * sizeof(int), stream);

    const int gemm_blocks = (N + 63) / 64;
    const int aggr_blocks = (N + 3) / 4;

    k_prep<<<2, 1024, 0, stream>>>(Wgat, atts, attd, Wgcn, Wt1, Wt2);
    k_bhist<<<(E + 2047) / 2048, 256, 0, stream>>>(ei + E, bcount, E, NB);
    k_gemm_mfma<<<gemm_blocks, 256, 0, stream>>>(x, Wt1, hb, N, 0,
                                                 nullptr, nullptr, nullptr,
                                                 nullptr, aS, aD);
    k_bscan<<<1, 512, 0, stream>>>(bcount, bb, bcur, NB);
    k_binA<<<(E + CHUNK_A - 1) / CHUNK_A, 256, 0, stream>>>(ei, bcur, pairs, E, NB);
    k_binB<<<NB, 256, 0, stream>>>(pairs, bb, csr, offs, dinv, N, NB, E);
    k_gat_aggr<<<aggr_blocks, 256, 0, stream>>>(hb, aS, aD, offs, csr, raw1, N);
    k_gemm_mfma<<<gemm_blocks, 256, 0, stream>>>(raw1, Wt2, h2b, N, 1,
                                                 bgat, bn1w, bn1b, dinv,
                                                 nullptr, nullptr);
    k_gcn_aggr<<<aggr_blocks, 256, 0, stream>>>(h2b, offs, csr, dinv, bgcn,
                                                bn2w, bn2b, wgate, bgate, wfc,
                                                gate, fcdot, N);
    k_pool<<<64, 256, 0, stream>>>(gate, fcdot, batch, bfc, out, N);
}